// Round 11
// baseline (1458.911 us; speedup 1.0000x reference)
//
#include <hip/hip_runtime.h>

#define BB 16
#define PP 100
#define EE 5
#define DD 128
#define GG 10
#define PD 12800      // P*D
#define KTD 12900     // PD + P
#define BPD (BB*PD)   // floats per level slab

typedef __attribute__((ext_vector_type(4))) float f32x4;
typedef __attribute__((ext_vector_type(8))) short short8;
typedef __attribute__((ext_vector_type(4))) short short4v;

static __device__ __forceinline__ short f2bf(float f) {
  unsigned u = __builtin_bit_cast(unsigned, f);
  u += 0x7FFFu + ((u >> 16) & 1u);
  return (short)(u >> 16);
}

static __device__ __forceinline__ short8 cvt8(float4 a, float4 b) {
  short8 r;
  r[0] = f2bf(a.x); r[1] = f2bf(a.y); r[2] = f2bf(a.z); r[3] = f2bf(a.w);
  r[4] = f2bf(b.x); r[5] = f2bf(b.y); r[6] = f2bf(b.z); r[7] = f2bf(b.w);
  return r;
}

// fire-and-forget global->LDS DMA. lds base must be wave-uniform; HW adds lane*size.
static __device__ __forceinline__ void gload16(const void* g, void* l) {
  __builtin_amdgcn_global_load_lds((const __attribute__((address_space(1))) void*)g,
                                   (__attribute__((address_space(3))) void*)l, 16, 0, 0);
}

// ---------------- encoder: patches -> conv -> relu -> fc -> broadcast to 5 levels
__global__ __launch_bounds__(128) void k_encoder(
    const float* __restrict__ x, const float* __restrict__ cw, const float* __restrict__ cb,
    const float* __restrict__ fw, const float* __restrict__ fb, float* __restrict__ cols) {
  int bid = blockIdx.x;            // b*100 + p
  int b = bid / 100, p = bid % 100;
  int py = p / 10, px = p % 10;
  __shared__ float patch[9];
  __shared__ float h[32];
  int tid = threadIdx.x;
  if (tid < 9) {
    int ii = tid / 3, jj = tid % 3;
    int gr = py * 3 + ii - 1, gc = px * 3 + jj - 1;
    float v = 0.f;
    if (gr >= 0 && gr < 28 && gc >= 0 && gc < 28) v = x[b * 784 + gr * 28 + gc];
    patch[tid] = v;
  }
  __syncthreads();
  if (tid < 32) {
    float a = cb[tid];
#pragma unroll
    for (int t = 0; t < 9; ++t) a += patch[t] * cw[tid * 9 + t];
    h[tid] = fmaxf(a, 0.f);
  }
  __syncthreads();
  float e = fb[tid];
#pragma unroll
  for (int o = 0; o < 32; ++o) e += h[o] * fw[tid * 32 + o];
  long bp = (long)b * PP + p;
  for (int lev = 0; lev < EE; ++lev)
    cols[((long)lev * BB * PP + bp) * DD + tid] = e;
}

// ---------------- fold pos columns of td_w into bias (pos is constant = arange(P))
__global__ __launch_bounds__(256) void k_tdbias(
    const float* __restrict__ td_w, const float* __restrict__ td_b, float* __restrict__ out) {
  int o = blockIdx.x * 256 + threadIdx.x;
  if (o >= PD) return;
  float s = td_b[o];
  const float4* r = (const float4*)(td_w + (long)o * KTD + PD);
#pragma unroll
  for (int q = 0; q < 25; ++q) {
    float4 v = r[q];
    float p0 = (float)(q * 4);
    s += p0 * v.x + (p0 + 1.f) * v.y + (p0 + 2.f) * v.z + (p0 + 3.f) * v.w;
  }
  out[o] = s;
}

#define MSTRIDE (1600L * 16 * 8)   // one 16-row block of packed A/W (shorts)

// ---------------- pack activations (80 rows x 12800) f32 -> bf16 tiles (initial only)
__global__ __launch_bounds__(256) void k_packa(
    const float* __restrict__ src, short* __restrict__ dst) {
  int bid = blockIdx.x;            // rb*8 + kc, RB=5
  int rb = bid / 8;
  int kc = bid % 8;
  int t = threadIdx.x;
  int r = t >> 4, c = t & 15;
  long srow = ((long)rb * 16 + r) * PD;
  for (int kk = 0; kk < 25; ++kk) {
    int k = kc * 1600 + kk * 64 + c * 4;
    float4 v = *(const float4*)(src + srow + k);
    short4v o;
    o[0] = f2bf(v.x); o[1] = f2bf(v.y); o[2] = f2bf(v.z); o[3] = f2bf(v.w);
    long di = (((long)rb * 1600 + (k >> 3)) * 16 + r) * 8 + (k & 7);
    *(short4v*)(dst + di) = o;
  }
}

// ---------------- step-0 fused GEMM v2: 256-k superstage, reg-staged B with 1KB
// contiguous row reads (content-swizzled LDS transpose), cvt in compute, MFMA,
// and emit packed bf16 weights. kc in {0,1} (6400 k each). grid 800 x 256thr.
__global__ __launch_bounds__(256) void k_gemm_f(
    const float* __restrict__ td_w, const float* __restrict__ bu_w,
    const short* __restrict__ Ap, short* __restrict__ wtd, short* __restrict__ wbu,
    float* __restrict__ ytd, float* __restrict__ ybu) {
  int bid = blockIdx.x;            // which*400 + kc*200 + nb
  int which = bid / 400;
  int r = bid % 400;
  int kc = r / 200;
  int nb = r % 200;
  int w = threadIdx.x >> 6;
  int lane = threadIdx.x & 63;
  int l15 = lane & 15, l4 = lane >> 4;
  const float* W = which ? bu_w : td_w;
  long ldw = which ? PD : KTD;
  short* WP = which ? wbu : wtd;
  float* Y = which ? ybu : ytd;
  int lev0 = which ? 0 : 1;
  int nb16 = nb * 4 + w;
  __shared__ float lBf[64 * 256];          // 64 KB [col][k-units content-swizzled]
  __shared__ short lA[2][4][4096];         // 64 KB [buf][level][32kg x 16 x 8]
  // B row pointers; per-lane k pre-swizzled: 16B-unit g stored at unit 2*((g>>1)^(row&7))+(g&1)
  const float* rp[16];
#pragma unroll
  for (int j = 0; j < 16; ++j)
    rp[j] = W + (long)(nb16 * 16 + j) * ldw + kc * 6400
          + (((lane >> 1) ^ (j & 7)) << 3) + ((lane & 1) << 2);
  const short* sA = Ap + (long)(lev0 + w) * MSTRIDE + (long)kc * 102400 + lane * 8;
  short* wp = WP + (long)nb16 * MSTRIDE + (long)kc * 102400;
  float4 c[16];
#define LOADB(ss) { _Pragma("unroll") \
  for (int j = 0; j < 16; ++j) c[j] = *(const float4*)(rp[j] + (ss) * 256); }
#define AGLOAD(buf, ss) { _Pragma("unroll") \
  for (int i = 0; i < 8; ++i) gload16(sA + (ss) * 4096 + i * 512, &lA[buf][w][i * 512]); }
  AGLOAD(0, 0)
  LOADB(0)
  f32x4 acc0 = {0,0,0,0}, acc1 = {0,0,0,0}, acc2 = {0,0,0,0}, acc3 = {0,0,0,0};
  for (int ss = 0; ss < 25; ++ss) {
    int cur = ss & 1;
#pragma unroll
    for (int j = 0; j < 16; ++j)       // contiguous 1KB LDS write per instr (wave-private rows)
      *(float4*)&lBf[(w * 16 + j) * 256 + lane * 4] = c[j];
    __syncthreads();                   // lA[cur] staged (cross-wave); lBf written
    if (ss < 24) { AGLOAD(cur ^ 1, ss + 1) LOADB(ss + 1) }
#pragma unroll
    for (int t = 0; t < 8; ++t) {
      int u = (t * 4 + l4) ^ (l15 & 7);
      const float* bp_ = &lBf[(w * 16 + l15) * 256 + u * 8];
      float4 b0 = *(const float4*)bp_;
      float4 b1 = *(const float4*)(bp_ + 4);
      short8 bF = cvt8(b0, b1);
      *(short8*)(wp + ((long)(ss * 32 + t * 4 + l4) * 16 + l15) * 8) = bF;
      int off = ((t * 4 + l4) * 16 + l15) * 8;
      short8 a0 = *(const short8*)&lA[cur][0][off];
      short8 a1 = *(const short8*)&lA[cur][1][off];
      short8 a2 = *(const short8*)&lA[cur][2][off];
      short8 a3 = *(const short8*)&lA[cur][3][off];
      acc0 = __builtin_amdgcn_mfma_f32_16x16x32_bf16(a0, bF, acc0, 0, 0, 0);
      acc1 = __builtin_amdgcn_mfma_f32_16x16x32_bf16(a1, bF, acc1, 0, 0, 0);
      acc2 = __builtin_amdgcn_mfma_f32_16x16x32_bf16(a2, bF, acc2, 0, 0, 0);
      acc3 = __builtin_amdgcn_mfma_f32_16x16x32_bf16(a3, bF, acc3, 0, 0, 0);
    }
  }
#undef LOADB
#undef AGLOAD
  float* yb = Y + (long)kc * 64 * PD;
  int col = nb16 * 16 + l15;
#pragma unroll
  for (int j = 0; j < 4; ++j) yb[(long)(0 * 16 + l4 * 4 + j) * PD + col] = acc0[j];
#pragma unroll
  for (int j = 0; j < 4; ++j) yb[(long)(1 * 16 + l4 * 4 + j) * PD + col] = acc1[j];
#pragma unroll
  for (int j = 0; j < 4; ++j) yb[(long)(2 * 16 + l4 * 4 + j) * PD + col] = acc2[j];
#pragma unroll
  for (int j = 0; j < 4; ++j) yb[(long)(3 * 16 + l4 * 4 + j) * PD + col] = acc3[j];
}

// ---------------- packed bf16 GEMM: global_load_lds double-buffered staging (kc in {0,1})
__global__ __launch_bounds__(256) void k_gemm_p(
    const short* __restrict__ Ap, const short* __restrict__ wtd,
    const short* __restrict__ wbu, float* __restrict__ ytd, float* __restrict__ ybu) {
  int bid = blockIdx.x;            // which*400 + kc*200 + nb
  int which = bid / 400;
  int r = bid % 400;
  int kc = r / 200;
  int nb = r % 200;
  int w = threadIdx.x >> 6;
  int lane = threadIdx.x & 63;
  int l15 = lane & 15, l4 = lane >> 4;
  const short* Wp = which ? wbu : wtd;
  float* Y = which ? ybu : ytd;
  int lev0 = which ? 0 : 1;
  int nb16 = nb * 4 + w;
  __shared__ short lA[2][4096];
  __shared__ short lB[2][4096];
  const short* sB = Wp + (long)nb16 * MSTRIDE + (long)kc * 102400 + lane * 8;
  const short* sA = Ap + (long)(lev0 + w) * MSTRIDE + (long)kc * 102400 + lane * 8;
  int lbase = w * 1024;
#define STAGE_G(bufi) { \
  gload16(sB,       &lB[bufi][lbase]); \
  gload16(sB + 512, &lB[bufi][lbase + 512]); \
  gload16(sA,       &lA[bufi][lbase]); \
  gload16(sA + 512, &lA[bufi][lbase + 512]); \
  sB += 1024; sA += 1024; }
  STAGE_G(0)
  f32x4 acc0 = {0,0,0,0}, acc1 = {0,0,0,0}, acc2 = {0,0,0,0}, acc3 = {0,0,0,0};
  int fo = l4 * 128 + l15 * 8;
  for (int s = 0; s < 100; ++s) {
    __syncthreads();
    int cur = s & 1;
    if (s < 99) STAGE_G(cur ^ 1)
#pragma unroll
    for (int ks = 0; ks < 2; ++ks) {
      int off = ks * 512 + fo;
      short8 bF = *(const short8*)&lB[cur][w * 1024 + off];
      short8 a0 = *(const short8*)&lA[cur][0 * 1024 + off];
      short8 a1 = *(const short8*)&lA[cur][1 * 1024 + off];
      short8 a2 = *(const short8*)&lA[cur][2 * 1024 + off];
      short8 a3 = *(const short8*)&lA[cur][3 * 1024 + off];
      acc0 = __builtin_amdgcn_mfma_f32_16x16x32_bf16(a0, bF, acc0, 0, 0, 0);
      acc1 = __builtin_amdgcn_mfma_f32_16x16x32_bf16(a1, bF, acc1, 0, 0, 0);
      acc2 = __builtin_amdgcn_mfma_f32_16x16x32_bf16(a2, bF, acc2, 0, 0, 0);
      acc3 = __builtin_amdgcn_mfma_f32_16x16x32_bf16(a3, bF, acc3, 0, 0, 0);
    }
  }
#undef STAGE_G
  float* yb = Y + (long)kc * 64 * PD;
  int col = nb16 * 16 + l15;
#pragma unroll
  for (int j = 0; j < 4; ++j) yb[(long)(0 * 16 + l4 * 4 + j) * PD + col] = acc0[j];
#pragma unroll
  for (int j = 0; j < 4; ++j) yb[(long)(1 * 16 + l4 * 4 + j) * PD + col] = acc1[j];
#pragma unroll
  for (int j = 0; j < 4; ++j) yb[(long)(2 * 16 + l4 * 4 + j) * PD + col] = acc2[j];
#pragma unroll
  for (int j = 0; j < 4; ++j) yb[(long)(3 * 16 + l4 * 4 + j) * PD + col] = acc3[j];
}

// ---------------- fallback f32-stream GEMM (used only if ws too small to pack)
__global__ __launch_bounds__(256) void k_gemm(
    const float* __restrict__ cols, const float* __restrict__ td_w,
    const float* __restrict__ bu_w, float* __restrict__ ytd, float* __restrict__ ybu) {
  int bid = blockIdx.x;            // which*400 + kc*200 + nb
  int which = bid / 400;
  int r = bid % 400;
  int kc = r / 200;
  int nb = r % 200;
  const float* X; const float* W; long ldw; float* Y;
  if (which == 0) { X = cols + BPD; W = td_w; ldw = KTD; Y = ytd; }
  else            { X = cols;       W = bu_w; ldw = PD;  Y = ybu; }
  int wave = threadIdx.x >> 6;
  int lane = threadIdx.x & 63;
  int l15 = lane & 15, l4 = lane >> 4;
  int n0 = nb * 64 + wave * 16;
  int k0 = kc * 6400 + l4 * 8;
  const float* ap = X + (long)l15 * PD + k0;
  const float* bp = W + (long)(n0 + l15) * ldw + k0;
  f32x4 acc[4] = {{0,0,0,0},{0,0,0,0},{0,0,0,0},{0,0,0,0}};
  for (int kk = 0; kk < 200; ++kk) {
    float4 b0 = *(const float4*)bp;
    float4 b1 = *(const float4*)(bp + 4);
    short8 bf = cvt8(b0, b1);
#pragma unroll
    for (int m = 0; m < 4; ++m) {
      const float* a_ = ap + (long)m * 16 * PD;
      float4 a0 = *(const float4*)a_;
      float4 a1 = *(const float4*)(a_ + 4);
      short8 af = cvt8(a0, a1);
      acc[m] = __builtin_amdgcn_mfma_f32_16x16x32_bf16(af, bf, acc[m], 0, 0, 0);
    }
    ap += 32; bp += 32;
  }
  float* yb = Y + (long)kc * 64 * PD;
  int col = n0 + l15;
#pragma unroll
  for (int m = 0; m < 4; ++m)
#pragma unroll
    for (int j = 0; j < 4; ++j)
      yb[(long)(m * 16 + l4 * 4 + j) * PD + col] = acc[m][j];
}

// ---------------- mega-fused attention + combine + next-step A packing
// grid 80 = (i*16+b); 256 threads; 153.6 KB LDS (T1, V, O; qg/kg/wbuf alias O).
__global__ __launch_bounds__(256) void k_att(
    const float* __restrict__ cols,
    const float* __restrict__ qw, const float* __restrict__ qb,
    const float* __restrict__ kw, const float* __restrict__ kb,
    const float* __restrict__ vw, const float* __restrict__ vb,
    const float* __restrict__ ytd, const float* __restrict__ ybu,
    const float* __restrict__ tdbias, const float* __restrict__ bub,
    const float* __restrict__ gamma,
    float* __restrict__ colsn, short* __restrict__ apack, int emit) {
  __shared__ float smem[38400];    // 153.6 KB
  float* T1 = smem;                // [100][128]
  float* V  = smem + 12800;        // [100][128]
  float* OL = smem + 25600;        // [100][128] (written in PV phase)
  float* QG = smem + 25600;        // [10][128]  (dead before OL writes)
  float* KG = smem + 26880;        // [10][128]
  float* WB = smem + 28160;        // [300]
  int ib = blockIdx.x;
  int i = ib >> 4, b = ib & 15;
  int t = threadIdx.x;
  const float* t1b = cols + (long)ib * PD;
  for (int idx = t; idx < PD; idx += 256) T1[idx] = t1b[idx];
  for (int idx = t; idx < 300; idx += 256) {
    int w3 = idx / 100, c = idx % 100;
    WB[idx] = (w3 == 0 ? qw[c] : w3 == 1 ? kw[c] : vw[c]);
  }
  __syncthreads();
  int s = t & 127, oh = t >> 7;    // gconv mapping: 2 o-reps per thread
  int mq = t & 3, nh = t >> 2;     // logits/PV mapping: rows nh and nh+64
  float acc0[32], acc1[32];
#pragma unroll
  for (int j = 0; j < 32; ++j) { acc0[j] = 0.f; acc1[j] = 0.f; }
  for (int g = 0; g < 10; ++g) {
    float aq[5], ak[5], av[5];
#pragma unroll
    for (int r = 0; r < 5; ++r) {
      int p = g * 10 + r * 2 + oh;
      aq[r] = qb[p]; ak[r] = kb[p]; av[r] = vb[p];
    }
    for (int c = 0; c < 10; ++c) {
      float z = T1[(g * 10 + c) * 128 + s];
#pragma unroll
      for (int r = 0; r < 5; ++r) {
        int o = r * 2 + oh;
        aq[r] += WB[o * 10 + c] * z;
        ak[r] += WB[100 + o * 10 + c] * z;
        av[r] += WB[200 + o * 10 + c] * z;
      }
    }
    __syncthreads();   // WB reads done; prior logits reads of QG/KG done (loop-end bar)
#pragma unroll
    for (int r = 0; r < 5; ++r) {
      int o = r * 2 + oh;
      QG[o * 128 + s] = aq[r];
      KG[o * 128 + s] = ak[r];
      V[(g * 10 + o) * 128 + s] = av[r];
    }
    if (g < 9) {
      for (int idx = t; idx < 300; idx += 256) {
        int w3 = idx / 100, c = idx % 100;
        int gi = (g + 1) * 100 + c;
        WB[idx] = (w3 == 0 ? qw[gi] : w3 == 1 ? kw[gi] : vw[gi]);
      }
    }
    __syncthreads();   // QG/KG + WB ready
    const float4* K4 = (const float4*)KG;
    for (int c = 0; c < 10; ++c) {
      float qa = QG[c * 128 + nh];
      float qc = QG[c * 128 + nh + 64];
#pragma unroll
      for (int jj = 0; jj < 8; ++jj) {
        float4 kv = K4[c * 32 + mq * 8 + jj];
        acc0[jj * 4 + 0] += qa * kv.x; acc0[jj * 4 + 1] += qa * kv.y;
        acc0[jj * 4 + 2] += qa * kv.z; acc0[jj * 4 + 3] += qa * kv.w;
        acc1[jj * 4 + 0] += qc * kv.x; acc1[jj * 4 + 1] += qc * kv.y;
        acc1[jj * 4 + 2] += qc * kv.z; acc1[jj * 4 + 3] += qc * kv.w;
      }
    }
    __syncthreads();   // QG/KG reads done before next g overwrites
  }
  // softmax over m for the two owned rows (4 lanes per row, mq in lane bits 0-1)
  {
    float mx = acc0[0];
#pragma unroll
    for (int j = 1; j < 32; ++j) mx = fmaxf(mx, acc0[j]);
    mx = fmaxf(mx, __shfl_xor(mx, 1)); mx = fmaxf(mx, __shfl_xor(mx, 2));
    float sm = 0.f;
#pragma unroll
    for (int j = 0; j < 32; ++j) { acc0[j] = __expf(acc0[j] - mx); sm += acc0[j]; }
    sm += __shfl_xor(sm, 1); sm += __shfl_xor(sm, 2);
    float inv = 1.0f / sm;
#pragma unroll
    for (int j = 0; j < 32; ++j) acc0[j] *= inv;
  }
  {
    float mx = acc1[0];
#pragma unroll
    for (int j = 1; j < 32; ++j) mx = fmaxf(mx, acc1[j]);
    mx = fmaxf(mx, __shfl_xor(mx, 1)); mx = fmaxf(mx, __shfl_xor(mx, 2));
    float sm = 0.f;
#pragma unroll
    for (int j = 0; j < 32; ++j) { acc1[j] = __expf(acc1[j] - mx); sm += acc1[j]; }
    sm += __shfl_xor(sm, 1); sm += __shfl_xor(sm, 2);
    float inv = 1.0f / sm;
#pragma unroll
    for (int j = 0; j < 32; ++j) acc1[j] *= inv;
  }
  // PV: O[p][n] = sum_m V[p][m] * A[n][m]; butterfly over mq; owner writes to LDS
  const float4* V4 = (const float4*)V;
  for (int p = 0; p < 100; ++p) {
    float pa = 0.f, pb = 0.f;
#pragma unroll
    for (int jj = 0; jj < 8; ++jj) {
      float4 vv = V4[p * 32 + mq * 8 + jj];
      pa += acc0[jj * 4 + 0] * vv.x + acc0[jj * 4 + 1] * vv.y
          + acc0[jj * 4 + 2] * vv.z + acc0[jj * 4 + 3] * vv.w;
      pb += acc1[jj * 4 + 0] * vv.x + acc1[jj * 4 + 1] * vv.y
          + acc1[jj * 4 + 2] * vv.z + acc1[jj * 4 + 3] * vv.w;
    }
    pa += __shfl_xor(pa, 1); pa += __shfl_xor(pa, 2);
    pb += __shfl_xor(pb, 1); pb += __shfl_xor(pb, 2);
    if ((p & 3) == mq) {
      OL[p * 128 + nh] = pa;
      OL[p * 128 + nh + 64] = pb;
    }
  }
  __syncthreads();
  // combine + emit packed bf16 A for next step (2 k-chunk partials now)
  float gam = gamma[0];
  bool has_td = (i < EE - 1);
  bool has_bu = (i > 0);
  const float* ytdr = ytd + ((long)i * BB + b) * PD;
  const float* ybur = ybu + ((long)(i - 1) * BB + b) * PD;
  const long CH = 64L * PD;
  float* outb = colsn + (long)ib * PD;
  short* ap_ = apack;
  for (int od = t; od < PD; od += 256) {
    float t1 = T1[od];
    float ov = OL[od];
    float accv = t1 + 0.33f * (gam * ov + t1);
    if (has_td) {
      float y = tdbias[od] + ytdr[od] + ytdr[CH + od];
      accv += 0.33f * y;
    }
    if (has_bu) {
      float y = bub[od] + ybur[od] + ybur[CH + od];
      accv += 0.33f * y;
    }
    outb[od] = accv;
    if (emit)
      ap_[(((long)i * 1600 + (od >> 3)) * 16 + b) * 8 + (od & 7)] = f2bf(accv);
  }
}

// ---------------- final: out[b][d] = mean_p cols[level 4][b][p][d]
__global__ __launch_bounds__(128) void k_mean(const float* __restrict__ cols, float* __restrict__ out) {
  int b = blockIdx.x, d = threadIdx.x;
  const float* base = cols + ((long)4 * BB + b) * PP * DD + d;
  float s0 = 0.f, s1 = 0.f, s2 = 0.f, s3 = 0.f;
  for (int p = 0; p < 100; p += 4) {
    s0 += base[(long)p * DD];
    s1 += base[(long)(p + 1) * DD];
    s2 += base[(long)(p + 2) * DD];
    s3 += base[(long)(p + 3) * DD];
  }
  out[b * DD + d] = (s0 + s1 + s2 + s3) / 100.0f;
}

extern "C" void kernel_launch(void* const* d_in, const int* in_sizes, int n_in,
                              void* d_out, int out_size, void* d_ws, size_t ws_size,
                              hipStream_t stream) {
  const float* x     = (const float*)d_in[0];
  const float* cnn_w = (const float*)d_in[1];
  const float* cnn_b = (const float*)d_in[2];
  const float* fc_w  = (const float*)d_in[3];
  const float* fc_b  = (const float*)d_in[4];
  const float* td_w  = (const float*)d_in[5];
  const float* td_b  = (const float*)d_in[6];
  const float* bu_w  = (const float*)d_in[7];
  const float* bu_b  = (const float*)d_in[8];
  const float* qw    = (const float*)d_in[9];
  const float* qb    = (const float*)d_in[10];
  const float* kw    = (const float*)d_in[11];
  const float* kb    = (const float*)d_in[12];
  const float* vw    = (const float*)d_in[13];
  const float* vb    = (const float*)d_in[14];
  const float* gamma = (const float*)d_in[15];
  float* out = (float*)d_out;
  float* ws = (float*)d_ws;

  float* cols_a = ws;                     // 1,024,000
  float* cols_b = ws + 1024000;           // 1,024,000
  float* ytd    = ws + 6430720;           // now [2][64][12800] = 1,638,400
  float* ybu    = ws + 9707520;           // now [2][64][12800] = 1,638,400
  float* tdbias = ws + 12984320;          // 12,800
  // packed bf16 region (shorts)
  short* wtd_p  = (short*)(ws + 12997120);          // 163,840,000 shorts
  short* wbu_p  = wtd_p + 163840000;                // 163,840,000 shorts
  short* apack  = wbu_p + 163840000;                // 1,024,000 shorts (+8192 pad)
  size_t need_bytes = (size_t)12997120 * 4 + (163840000ULL * 2 + 1024000ULL + 8192ULL) * 2;
  bool packed = ws_size >= need_bytes;

  k_encoder<<<1600, 128, 0, stream>>>(x, cnn_w, cnn_b, fc_w, fc_b, cols_a);
  k_tdbias<<<50, 256, 0, stream>>>(td_w, td_b, tdbias);
  if (packed) k_packa<<<40, 256, 0, stream>>>(cols_a, apack);

  float* cur = cols_a;
  float* nxt = cols_b;
  for (int t = 0; t < 3; ++t) {
    if (packed) {
      if (t == 0)
        k_gemm_f<<<800, 256, 0, stream>>>(td_w, bu_w, apack, wtd_p, wbu_p, ytd, ybu);
      else
        k_gemm_p<<<800, 256, 0, stream>>>(apack, wtd_p, wbu_p, ytd, ybu);
    } else {
      k_gemm<<<800, 256, 0, stream>>>(cur, td_w, bu_w, ytd, ybu);
    }
    int emit = (packed && t < 2) ? 1 : 0;
    k_att<<<80, 256, 0, stream>>>(cur, qw, qb, kw, kb, vw, vb,
                                  ytd, ybu, tdbias, bu_b, gamma, nxt, apack, emit);
    float* tmp = cur; cur = nxt; nxt = tmp;
  }
  k_mean<<<16, 128, 0, stream>>>(cur, out);
}

// Round 12
// 1118.669 us; speedup vs baseline: 1.3041x; 1.3041x over previous
//
#include <hip/hip_runtime.h>

#define BB 16
#define PP 100
#define EE 5
#define DD 128
#define GG 10
#define PD 12800      // P*D
#define KTD 12900     // PD + P
#define BPD (BB*PD)   // floats per level slab

typedef __attribute__((ext_vector_type(4))) float f32x4;
typedef __attribute__((ext_vector_type(8))) short short8;
typedef __attribute__((ext_vector_type(4))) short short4v;

static __device__ __forceinline__ short f2bf(float f) {
  unsigned u = __builtin_bit_cast(unsigned, f);
  u += 0x7FFFu + ((u >> 16) & 1u);
  return (short)(u >> 16);
}

static __device__ __forceinline__ short8 cvt8(float4 a, float4 b) {
  short8 r;
  r[0] = f2bf(a.x); r[1] = f2bf(a.y); r[2] = f2bf(a.z); r[3] = f2bf(a.w);
  r[4] = f2bf(b.x); r[5] = f2bf(b.y); r[6] = f2bf(b.z); r[7] = f2bf(b.w);
  return r;
}

// fire-and-forget global->LDS DMA. lds base must be wave-uniform; HW adds lane*size.
static __device__ __forceinline__ void gload16(const void* g, void* l) {
  __builtin_amdgcn_global_load_lds((const __attribute__((address_space(1))) void*)g,
                                   (__attribute__((address_space(3))) void*)l, 16, 0, 0);
}

// ---------------- encoder: patches -> conv -> relu -> fc -> broadcast to 5 levels
__global__ __launch_bounds__(128) void k_encoder(
    const float* __restrict__ x, const float* __restrict__ cw, const float* __restrict__ cb,
    const float* __restrict__ fw, const float* __restrict__ fb, float* __restrict__ cols) {
  int bid = blockIdx.x;            // b*100 + p
  int b = bid / 100, p = bid % 100;
  int py = p / 10, px = p % 10;
  __shared__ float patch[9];
  __shared__ float h[32];
  int tid = threadIdx.x;
  if (tid < 9) {
    int ii = tid / 3, jj = tid % 3;
    int gr = py * 3 + ii - 1, gc = px * 3 + jj - 1;
    float v = 0.f;
    if (gr >= 0 && gr < 28 && gc >= 0 && gc < 28) v = x[b * 784 + gr * 28 + gc];
    patch[tid] = v;
  }
  __syncthreads();
  if (tid < 32) {
    float a = cb[tid];
#pragma unroll
    for (int t = 0; t < 9; ++t) a += patch[t] * cw[tid * 9 + t];
    h[tid] = fmaxf(a, 0.f);
  }
  __syncthreads();
  float e = fb[tid];
#pragma unroll
  for (int o = 0; o < 32; ++o) e += h[o] * fw[tid * 32 + o];
  long bp = (long)b * PP + p;
  for (int lev = 0; lev < EE; ++lev)
    cols[((long)lev * BB * PP + bp) * DD + tid] = e;
}

// ---------------- fold pos columns of td_w into bias (pos is constant = arange(P))
__global__ __launch_bounds__(256) void k_tdbias(
    const float* __restrict__ td_w, const float* __restrict__ td_b, float* __restrict__ out) {
  int o = blockIdx.x * 256 + threadIdx.x;
  if (o >= PD) return;
  float s = td_b[o];
  const float4* r = (const float4*)(td_w + (long)o * KTD + PD);
#pragma unroll
  for (int q = 0; q < 25; ++q) {
    float4 v = r[q];
    float p0 = (float)(q * 4);
    s += p0 * v.x + (p0 + 1.f) * v.y + (p0 + 2.f) * v.z + (p0 + 3.f) * v.w;
  }
  out[o] = s;
}

#define MSTRIDE (1600L * 16 * 8)   // one 16-row block of packed A/W (shorts)

// ---------------- pack activations (80 rows x 12800) f32 -> bf16 tiles (initial only)
__global__ __launch_bounds__(256) void k_packa(
    const float* __restrict__ src, short* __restrict__ dst) {
  int bid = blockIdx.x;            // rb*8 + kc, RB=5
  int rb = bid / 8;
  int kc = bid % 8;
  int t = threadIdx.x;
  int r = t >> 4, c = t & 15;
  long srow = ((long)rb * 16 + r) * PD;
  for (int kk = 0; kk < 25; ++kk) {
    int k = kc * 1600 + kk * 64 + c * 4;
    float4 v = *(const float4*)(src + srow + k);
    short4v o;
    o[0] = f2bf(v.x); o[1] = f2bf(v.y); o[2] = f2bf(v.z); o[3] = f2bf(v.w);
    long di = (((long)rb * 1600 + (k >> 3)) * 16 + r) * 8 + (k & 7);
    *(short4v*)(dst + di) = o;
  }
}

// ---------------- step-0 fused GEMM: stage f32 weights via 4x gload16 (4 rows x 256B
// segments per instr, xor-swizzled source), convert in compute phase, MFMA, and emit
// packed bf16 weights for steps 1-2. Same LDS layout/read path as the proven R10 kernel.
__global__ __launch_bounds__(256) void k_gemm_f(
    const float* __restrict__ td_w, const float* __restrict__ bu_w,
    const short* __restrict__ Ap, short* __restrict__ wtd, short* __restrict__ wbu,
    float* __restrict__ ytd, float* __restrict__ ybu) {
  int bid = blockIdx.x;            // which*800 + kc*200 + nb
  int which = bid / 800;
  int r = bid % 800;
  int kc = r / 200;
  int nb = r % 200;
  int w = threadIdx.x >> 6;
  int lane = threadIdx.x & 63;
  int l15 = lane & 15, l4 = lane >> 4;
  const float* W = which ? bu_w : td_w;
  long ldw = which ? PD : KTD;
  short* WP = which ? wbu : wtd;
  float* Y = which ? ybu : ytd;
  int lev0 = which ? 0 : 1;
  int nb16 = nb * 4 + w;
  __shared__ float lBf[2][4096];   // per wave: [col 16][k 64] f32, k xor-swizzled by col
  __shared__ short lA[2][4096];    // [level][kg 0..7][row 16][k 8] bf16
  // B source: instr q covers cols q*4+(lane>>4); content chunk g holds source chunk g^(c&7)
  const float* bsrc[4];
#pragma unroll
  for (int q = 0; q < 4; ++q) {
    int c = q * 4 + (lane >> 4);
    bsrc[q] = W + (long)(nb16 * 16 + c) * ldw + kc * 3200
            + (((lane & 15) * 4) ^ ((c & 7) * 8));
  }
  const short* sA = Ap + (long)(lev0 + w) * MSTRIDE + (long)kc * 51200 + lane * 8;
  short* wp = WP + (long)nb16 * MSTRIDE + (((long)kc * 400 + l4) * 16 + l15) * 8;
  int lbase = w * 1024;            // wave-uniform offset (floats / shorts)
#define STAGE_F(bufi) { \
  float* bdst = lBf[bufi]; short* adst = lA[bufi]; \
  gload16(bsrc[0], bdst + lbase); \
  gload16(bsrc[1], bdst + lbase + 256); \
  gload16(bsrc[2], bdst + lbase + 512); \
  gload16(bsrc[3], bdst + lbase + 768); \
  gload16(sA, adst + lbase); \
  gload16(sA + 512, adst + lbase + 512); \
  bsrc[0] += 64; bsrc[1] += 64; bsrc[2] += 64; bsrc[3] += 64; \
  sA += 1024; }
  STAGE_F(0)
  f32x4 acc0 = {0,0,0,0}, acc1 = {0,0,0,0}, acc2 = {0,0,0,0}, acc3 = {0,0,0,0};
  int bswz = (l15 & 7) * 8;
  for (int s = 0; s < 50; ++s) {
    __syncthreads();               // stage(s) landed for all waves
    int cur = s & 1;
    if (s < 49) STAGE_F(cur ^ 1)
#pragma unroll
    for (int ks = 0; ks < 2; ++ks) {
      int fb_ = lbase + l15 * 64 + ((ks * 32 + l4 * 8) ^ bswz);
      float4 b0 = *(const float4*)&lBf[cur][fb_];
      float4 b1 = *(const float4*)&lBf[cur][fb_ + 4];
      short8 bF = cvt8(b0, b1);
      *(short8*)(wp + (long)(s * 8 + ks * 4) * 128) = bF;   // emit packed weights
      int off = ks * 512 + l4 * 128 + l15 * 8;
      short8 a0 = *(const short8*)&lA[cur][0 * 1024 + off];
      short8 a1 = *(const short8*)&lA[cur][1 * 1024 + off];
      short8 a2 = *(const short8*)&lA[cur][2 * 1024 + off];
      short8 a3 = *(const short8*)&lA[cur][3 * 1024 + off];
      acc0 = __builtin_amdgcn_mfma_f32_16x16x32_bf16(a0, bF, acc0, 0, 0, 0);
      acc1 = __builtin_amdgcn_mfma_f32_16x16x32_bf16(a1, bF, acc1, 0, 0, 0);
      acc2 = __builtin_amdgcn_mfma_f32_16x16x32_bf16(a2, bF, acc2, 0, 0, 0);
      acc3 = __builtin_amdgcn_mfma_f32_16x16x32_bf16(a3, bF, acc3, 0, 0, 0);
    }
  }
#undef STAGE_F
  float* yb = Y + (long)kc * 64 * PD;
  int col = nb16 * 16 + l15;
#pragma unroll
  for (int j = 0; j < 4; ++j) yb[(long)(0 * 16 + l4 * 4 + j) * PD + col] = acc0[j];
#pragma unroll
  for (int j = 0; j < 4; ++j) yb[(long)(1 * 16 + l4 * 4 + j) * PD + col] = acc1[j];
#pragma unroll
  for (int j = 0; j < 4; ++j) yb[(long)(2 * 16 + l4 * 4 + j) * PD + col] = acc2[j];
#pragma unroll
  for (int j = 0; j < 4; ++j) yb[(long)(3 * 16 + l4 * 4 + j) * PD + col] = acc3[j];
}

// ---------------- packed bf16 GEMM: global_load_lds double-buffered staging
__global__ __launch_bounds__(256) void k_gemm_p(
    const short* __restrict__ Ap, const short* __restrict__ wtd,
    const short* __restrict__ wbu, float* __restrict__ ytd, float* __restrict__ ybu) {
  int bid = blockIdx.x;            // which*800 + kc*200 + nb
  int which = bid / 800;
  int r = bid % 800;
  int kc = r / 200;
  int nb = r % 200;
  int w = threadIdx.x >> 6;
  int lane = threadIdx.x & 63;
  int l15 = lane & 15, l4 = lane >> 4;
  const short* Wp = which ? wbu : wtd;
  float* Y = which ? ybu : ytd;
  int lev0 = which ? 0 : 1;
  int nb16 = nb * 4 + w;
  __shared__ short lA[2][4096];
  __shared__ short lB[2][4096];
  const short* sB = Wp + (long)nb16 * MSTRIDE + (long)kc * 51200 + lane * 8;
  const short* sA = Ap + (long)(lev0 + w) * MSTRIDE + (long)kc * 51200 + lane * 8;
  int lbase = w * 1024;
#define STAGE_G(bufi) { \
  gload16(sB,       &lB[bufi][lbase]); \
  gload16(sB + 512, &lB[bufi][lbase + 512]); \
  gload16(sA,       &lA[bufi][lbase]); \
  gload16(sA + 512, &lA[bufi][lbase + 512]); \
  sB += 1024; sA += 1024; }
  STAGE_G(0)
  f32x4 acc0 = {0,0,0,0}, acc1 = {0,0,0,0}, acc2 = {0,0,0,0}, acc3 = {0,0,0,0};
  int fo = l4 * 128 + l15 * 8;
  for (int s = 0; s < 50; ++s) {
    __syncthreads();
    int cur = s & 1;
    if (s < 49) STAGE_G(cur ^ 1)
#pragma unroll
    for (int ks = 0; ks < 2; ++ks) {
      int off = ks * 512 + fo;
      short8 bF = *(const short8*)&lB[cur][w * 1024 + off];
      short8 a0 = *(const short8*)&lA[cur][0 * 1024 + off];
      short8 a1 = *(const short8*)&lA[cur][1 * 1024 + off];
      short8 a2 = *(const short8*)&lA[cur][2 * 1024 + off];
      short8 a3 = *(const short8*)&lA[cur][3 * 1024 + off];
      acc0 = __builtin_amdgcn_mfma_f32_16x16x32_bf16(a0, bF, acc0, 0, 0, 0);
      acc1 = __builtin_amdgcn_mfma_f32_16x16x32_bf16(a1, bF, acc1, 0, 0, 0);
      acc2 = __builtin_amdgcn_mfma_f32_16x16x32_bf16(a2, bF, acc2, 0, 0, 0);
      acc3 = __builtin_amdgcn_mfma_f32_16x16x32_bf16(a3, bF, acc3, 0, 0, 0);
    }
  }
#undef STAGE_G
  float* yb = Y + (long)kc * 64 * PD;
  int col = nb16 * 16 + l15;
#pragma unroll
  for (int j = 0; j < 4; ++j) yb[(long)(0 * 16 + l4 * 4 + j) * PD + col] = acc0[j];
#pragma unroll
  for (int j = 0; j < 4; ++j) yb[(long)(1 * 16 + l4 * 4 + j) * PD + col] = acc1[j];
#pragma unroll
  for (int j = 0; j < 4; ++j) yb[(long)(2 * 16 + l4 * 4 + j) * PD + col] = acc2[j];
#pragma unroll
  for (int j = 0; j < 4; ++j) yb[(long)(3 * 16 + l4 * 4 + j) * PD + col] = acc3[j];
}

// ---------------- fallback f32-stream GEMM (used only if ws too small to pack)
__global__ __launch_bounds__(256) void k_gemm(
    const float* __restrict__ cols, const float* __restrict__ td_w,
    const float* __restrict__ bu_w, float* __restrict__ ytd, float* __restrict__ ybu) {
  int bid = blockIdx.x;            // 0..1599
  int which = bid / 800;
  int r = bid % 800;
  int kc = r / 200;
  int nb = r % 200;
  const float* X; const float* W; long ldw; float* Y;
  if (which == 0) { X = cols + BPD; W = td_w; ldw = KTD; Y = ytd; }
  else            { X = cols;       W = bu_w; ldw = PD;  Y = ybu; }
  int wave = threadIdx.x >> 6;
  int lane = threadIdx.x & 63;
  int l15 = lane & 15, l4 = lane >> 4;
  int n0 = nb * 64 + wave * 16;
  int k0 = kc * 3200 + l4 * 8;
  const float* ap = X + (long)l15 * PD + k0;
  const float* bp = W + (long)(n0 + l15) * ldw + k0;
  f32x4 acc[4] = {{0,0,0,0},{0,0,0,0},{0,0,0,0},{0,0,0,0}};
  for (int kk = 0; kk < 100; ++kk) {
    float4 b0 = *(const float4*)bp;
    float4 b1 = *(const float4*)(bp + 4);
    short8 bf = cvt8(b0, b1);
#pragma unroll
    for (int m = 0; m < 4; ++m) {
      const float* a_ = ap + (long)m * 16 * PD;
      float4 a0 = *(const float4*)a_;
      float4 a1 = *(const float4*)(a_ + 4);
      short8 af = cvt8(a0, a1);
      acc[m] = __builtin_amdgcn_mfma_f32_16x16x32_bf16(af, bf, acc[m], 0, 0, 0);
    }
    ap += 32; bp += 32;
  }
  float* yb = Y + (long)kc * 64 * PD;
  int col = n0 + l15;
#pragma unroll
  for (int m = 0; m < 4; ++m)
#pragma unroll
    for (int j = 0; j < 4; ++j)
      yb[(long)(m * 16 + l4 * 4 + j) * PD + col] = acc[m][j];
}

// ---------------- mega-fused attention + combine + next-step A packing
// grid 80 = (i*16+b); 256 threads; 153.6 KB LDS (T1, V, O; qg/kg/wbuf alias O).
__global__ __launch_bounds__(256) void k_att(
    const float* __restrict__ cols,
    const float* __restrict__ qw, const float* __restrict__ qb,
    const float* __restrict__ kw, const float* __restrict__ kb,
    const float* __restrict__ vw, const float* __restrict__ vb,
    const float* __restrict__ ytd, const float* __restrict__ ybu,
    const float* __restrict__ tdbias, const float* __restrict__ bub,
    const float* __restrict__ gamma,
    float* __restrict__ colsn, short* __restrict__ apack, int emit) {
  __shared__ float smem[38400];    // 153.6 KB
  float* T1 = smem;                // [100][128]
  float* V  = smem + 12800;        // [100][128]
  float* OL = smem + 25600;        // [100][128] (written in PV phase)
  float* QG = smem + 25600;        // [10][128]  (dead before OL writes)
  float* KG = smem + 26880;        // [10][128]
  float* WB = smem + 28160;        // [300]
  int ib = blockIdx.x;
  int i = ib >> 4, b = ib & 15;
  int t = threadIdx.x;
  const float* t1b = cols + (long)ib * PD;
  for (int idx = t; idx < PD; idx += 256) T1[idx] = t1b[idx];
  for (int idx = t; idx < 300; idx += 256) {
    int w3 = idx / 100, c = idx % 100;
    WB[idx] = (w3 == 0 ? qw[c] : w3 == 1 ? kw[c] : vw[c]);
  }
  __syncthreads();
  int s = t & 127, oh = t >> 7;    // gconv mapping: 2 o-reps per thread
  int mq = t & 3, nh = t >> 2;     // logits/PV mapping: rows nh and nh+64
  float acc0[32], acc1[32];
#pragma unroll
  for (int j = 0; j < 32; ++j) { acc0[j] = 0.f; acc1[j] = 0.f; }
  for (int g = 0; g < 10; ++g) {
    float aq[5], ak[5], av[5];
#pragma unroll
    for (int r = 0; r < 5; ++r) {
      int p = g * 10 + r * 2 + oh;
      aq[r] = qb[p]; ak[r] = kb[p]; av[r] = vb[p];
    }
    for (int c = 0; c < 10; ++c) {
      float z = T1[(g * 10 + c) * 128 + s];
#pragma unroll
      for (int r = 0; r < 5; ++r) {
        int o = r * 2 + oh;
        aq[r] += WB[o * 10 + c] * z;
        ak[r] += WB[100 + o * 10 + c] * z;
        av[r] += WB[200 + o * 10 + c] * z;
      }
    }
    __syncthreads();   // WB reads done; prior logits reads of QG/KG done (loop-end bar)
#pragma unroll
    for (int r = 0; r < 5; ++r) {
      int o = r * 2 + oh;
      QG[o * 128 + s] = aq[r];
      KG[o * 128 + s] = ak[r];
      V[(g * 10 + o) * 128 + s] = av[r];
    }
    if (g < 9) {
      for (int idx = t; idx < 300; idx += 256) {
        int w3 = idx / 100, c = idx % 100;
        int gi = (g + 1) * 100 + c;
        WB[idx] = (w3 == 0 ? qw[gi] : w3 == 1 ? kw[gi] : vw[gi]);
      }
    }
    __syncthreads();   // QG/KG + WB ready
    const float4* K4 = (const float4*)KG;
    for (int c = 0; c < 10; ++c) {
      float qa = QG[c * 128 + nh];
      float qc = QG[c * 128 + nh + 64];
#pragma unroll
      for (int jj = 0; jj < 8; ++jj) {
        float4 kv = K4[c * 32 + mq * 8 + jj];
        acc0[jj * 4 + 0] += qa * kv.x; acc0[jj * 4 + 1] += qa * kv.y;
        acc0[jj * 4 + 2] += qa * kv.z; acc0[jj * 4 + 3] += qa * kv.w;
        acc1[jj * 4 + 0] += qc * kv.x; acc1[jj * 4 + 1] += qc * kv.y;
        acc1[jj * 4 + 2] += qc * kv.z; acc1[jj * 4 + 3] += qc * kv.w;
      }
    }
    __syncthreads();   // QG/KG reads done before next g overwrites
  }
  // softmax over m for the two owned rows (4 lanes per row, mq in lane bits 0-1)
  {
    float mx = acc0[0];
#pragma unroll
    for (int j = 1; j < 32; ++j) mx = fmaxf(mx, acc0[j]);
    mx = fmaxf(mx, __shfl_xor(mx, 1)); mx = fmaxf(mx, __shfl_xor(mx, 2));
    float sm = 0.f;
#pragma unroll
    for (int j = 0; j < 32; ++j) { acc0[j] = __expf(acc0[j] - mx); sm += acc0[j]; }
    sm += __shfl_xor(sm, 1); sm += __shfl_xor(sm, 2);
    float inv = 1.0f / sm;
#pragma unroll
    for (int j = 0; j < 32; ++j) acc0[j] *= inv;
  }
  {
    float mx = acc1[0];
#pragma unroll
    for (int j = 1; j < 32; ++j) mx = fmaxf(mx, acc1[j]);
    mx = fmaxf(mx, __shfl_xor(mx, 1)); mx = fmaxf(mx, __shfl_xor(mx, 2));
    float sm = 0.f;
#pragma unroll
    for (int j = 0; j < 32; ++j) { acc1[j] = __expf(acc1[j] - mx); sm += acc1[j]; }
    sm += __shfl_xor(sm, 1); sm += __shfl_xor(sm, 2);
    float inv = 1.0f / sm;
#pragma unroll
    for (int j = 0; j < 32; ++j) acc1[j] *= inv;
  }
  // PV: O[p][n] = sum_m V[p][m] * A[n][m]; butterfly over mq; owner writes to LDS
  const float4* V4 = (const float4*)V;
  for (int p = 0; p < 100; ++p) {
    float pa = 0.f, pb = 0.f;
#pragma unroll
    for (int jj = 0; jj < 8; ++jj) {
      float4 vv = V4[p * 32 + mq * 8 + jj];
      pa += acc0[jj * 4 + 0] * vv.x + acc0[jj * 4 + 1] * vv.y
          + acc0[jj * 4 + 2] * vv.z + acc0[jj * 4 + 3] * vv.w;
      pb += acc1[jj * 4 + 0] * vv.x + acc1[jj * 4 + 1] * vv.y
          + acc1[jj * 4 + 2] * vv.z + acc1[jj * 4 + 3] * vv.w;
    }
    pa += __shfl_xor(pa, 1); pa += __shfl_xor(pa, 2);
    pb += __shfl_xor(pb, 1); pb += __shfl_xor(pb, 2);
    if ((p & 3) == mq) {
      OL[p * 128 + nh] = pa;
      OL[p * 128 + nh + 64] = pb;
    }
  }
  __syncthreads();
  // combine + emit packed bf16 A for next step
  float gam = gamma[0];
  bool has_td = (i < EE - 1);
  bool has_bu = (i > 0);
  const float* ytdr = ytd + ((long)i * BB + b) * PD;
  const float* ybur = ybu + ((long)(i - 1) * BB + b) * PD;
  const long CH = 64L * PD;
  float* outb = colsn + (long)ib * PD;
  short* ap_ = apack;
  for (int od = t; od < PD; od += 256) {
    float t1 = T1[od];
    float ov = OL[od];
    float accv = t1 + 0.33f * (gam * ov + t1);
    if (has_td) {
      float y = tdbias[od] + ytdr[od] + ytdr[CH + od] + ytdr[2 * CH + od] + ytdr[3 * CH + od];
      accv += 0.33f * y;
    }
    if (has_bu) {
      float y = bub[od] + ybur[od] + ybur[CH + od] + ybur[2 * CH + od] + ybur[3 * CH + od];
      accv += 0.33f * y;
    }
    outb[od] = accv;
    if (emit)
      ap_[(((long)i * 1600 + (od >> 3)) * 16 + b) * 8 + (od & 7)] = f2bf(accv);
  }
}

// ---------------- final: out[b][d] = mean_p cols[level 4][b][p][d]
__global__ __launch_bounds__(128) void k_mean(const float* __restrict__ cols, float* __restrict__ out) {
  int b = blockIdx.x, d = threadIdx.x;
  const float* base = cols + ((long)4 * BB + b) * PP * DD + d;
  float s0 = 0.f, s1 = 0.f, s2 = 0.f, s3 = 0.f;
  for (int p = 0; p < 100; p += 4) {
    s0 += base[(long)p * DD];
    s1 += base[(long)(p + 1) * DD];
    s2 += base[(long)(p + 2) * DD];
    s3 += base[(long)(p + 3) * DD];
  }
  out[b * DD + d] = (s0 + s1 + s2 + s3) / 100.0f;
}

extern "C" void kernel_launch(void* const* d_in, const int* in_sizes, int n_in,
                              void* d_out, int out_size, void* d_ws, size_t ws_size,
                              hipStream_t stream) {
  const float* x     = (const float*)d_in[0];
  const float* cnn_w = (const float*)d_in[1];
  const float* cnn_b = (const float*)d_in[2];
  const float* fc_w  = (const float*)d_in[3];
  const float* fc_b  = (const float*)d_in[4];
  const float* td_w  = (const float*)d_in[5];
  const float* td_b  = (const float*)d_in[6];
  const float* bu_w  = (const float*)d_in[7];
  const float* bu_b  = (const float*)d_in[8];
  const float* qw    = (const float*)d_in[9];
  const float* qb    = (const float*)d_in[10];
  const float* kw    = (const float*)d_in[11];
  const float* kb    = (const float*)d_in[12];
  const float* vw    = (const float*)d_in[13];
  const float* vb    = (const float*)d_in[14];
  const float* gamma = (const float*)d_in[15];
  float* out = (float*)d_out;
  float* ws = (float*)d_ws;

  float* cols_a = ws;                     // 1,024,000
  float* cols_b = ws + 1024000;           // 1,024,000
  float* ytd    = ws + 6430720;           // 3,276,800
  float* ybu    = ws + 9707520;           // 3,276,800
  float* tdbias = ws + 12984320;          // 12,800
  // packed bf16 region (shorts)
  short* wtd_p  = (short*)(ws + 12997120);          // 163,840,000 shorts
  short* wbu_p  = wtd_p + 163840000;                // 163,840,000 shorts
  short* apack  = wbu_p + 163840000;                // 1,024,000 shorts (+8192 pad)
  size_t need_bytes = (size_t)12997120 * 4 + (163840000ULL * 2 + 1024000ULL + 8192ULL) * 2;
  bool packed = ws_size >= need_bytes;

  k_encoder<<<1600, 128, 0, stream>>>(x, cnn_w, cnn_b, fc_w, fc_b, cols_a);
  k_tdbias<<<50, 256, 0, stream>>>(td_w, td_b, tdbias);
  if (packed) k_packa<<<40, 256, 0, stream>>>(cols_a, apack);

  float* cur = cols_a;
  float* nxt = cols_b;
  for (int t = 0; t < 3; ++t) {
    if (packed) {
      if (t == 0)
        k_gemm_f<<<1600, 256, 0, stream>>>(td_w, bu_w, apack, wtd_p, wbu_p, ytd, ybu);
      else
        k_gemm_p<<<1600, 256, 0, stream>>>(apack, wtd_p, wbu_p, ytd, ybu);
    } else {
      k_gemm<<<1600, 256, 0, stream>>>(cur, td_w, bu_w, ytd, ybu);
    }
    int emit = (packed && t < 2) ? 1 : 0;
    k_att<<<80, 256, 0, stream>>>(cur, qw, qb, kw, kb, vw, vb,
                                  ytd, ybu, tdbias, bu_b, gamma, nxt, apack, emit);
    float* tmp = cur; cur = nxt; nxt = tmp;
  }
  k_mean<<<16, 128, 0, stream>>>(cur, out);
}

// Round 13
// 1071.805 us; speedup vs baseline: 1.3612x; 1.0437x over previous
//
#include <hip/hip_runtime.h>

#define BB 16
#define PP 100
#define EE 5
#define DD 128
#define GG 10
#define PD 12800      // P*D
#define KTD 12900     // PD + P
#define BPD (BB*PD)   // floats per level slab

typedef __attribute__((ext_vector_type(4))) float f32x4;
typedef __attribute__((ext_vector_type(8))) short short8;
typedef __attribute__((ext_vector_type(4))) short short4v;

static __device__ __forceinline__ short f2bf(float f) {
  unsigned u = __builtin_bit_cast(unsigned, f);
  u += 0x7FFFu + ((u >> 16) & 1u);
  return (short)(u >> 16);
}

static __device__ __forceinline__ short8 cvt8(float4 a, float4 b) {
  short8 r;
  r[0] = f2bf(a.x); r[1] = f2bf(a.y); r[2] = f2bf(a.z); r[3] = f2bf(a.w);
  r[4] = f2bf(b.x); r[5] = f2bf(b.y); r[6] = f2bf(b.z); r[7] = f2bf(b.w);
  return r;
}

// fire-and-forget global->LDS DMA. lds base must be wave-uniform; HW adds lane*size.
static __device__ __forceinline__ void gload16(const void* g, void* l) {
  __builtin_amdgcn_global_load_lds((const __attribute__((address_space(1))) void*)g,
                                   (__attribute__((address_space(3))) void*)l, 16, 0, 0);
}

// ---------------- encoder: patches -> conv -> relu -> fc -> broadcast to 5 levels
__global__ __launch_bounds__(128) void k_encoder(
    const float* __restrict__ x, const float* __restrict__ cw, const float* __restrict__ cb,
    const float* __restrict__ fw, const float* __restrict__ fb, float* __restrict__ cols) {
  int bid = blockIdx.x;            // b*100 + p
  int b = bid / 100, p = bid % 100;
  int py = p / 10, px = p % 10;
  __shared__ float patch[9];
  __shared__ float h[32];
  int tid = threadIdx.x;
  if (tid < 9) {
    int ii = tid / 3, jj = tid % 3;
    int gr = py * 3 + ii - 1, gc = px * 3 + jj - 1;
    float v = 0.f;
    if (gr >= 0 && gr < 28 && gc >= 0 && gc < 28) v = x[b * 784 + gr * 28 + gc];
    patch[tid] = v;
  }
  __syncthreads();
  if (tid < 32) {
    float a = cb[tid];
#pragma unroll
    for (int t = 0; t < 9; ++t) a += patch[t] * cw[tid * 9 + t];
    h[tid] = fmaxf(a, 0.f);
  }
  __syncthreads();
  float e = fb[tid];
#pragma unroll
  for (int o = 0; o < 32; ++o) e += h[o] * fw[tid * 32 + o];
  long bp = (long)b * PP + p;
  for (int lev = 0; lev < EE; ++lev)
    cols[((long)lev * BB * PP + bp) * DD + tid] = e;
}

// ---------------- fold pos columns of td_w into bias (pos is constant = arange(P))
__global__ __launch_bounds__(256) void k_tdbias(
    const float* __restrict__ td_w, const float* __restrict__ td_b, float* __restrict__ out) {
  int o = blockIdx.x * 256 + threadIdx.x;
  if (o >= PD) return;
  float s = td_b[o];
  const float4* r = (const float4*)(td_w + (long)o * KTD + PD);
#pragma unroll
  for (int q = 0; q < 25; ++q) {
    float4 v = r[q];
    float p0 = (float)(q * 4);
    s += p0 * v.x + (p0 + 1.f) * v.y + (p0 + 2.f) * v.z + (p0 + 3.f) * v.w;
  }
  out[o] = s;
}

#define MSTRIDE (1600L * 16 * 8)   // one 16-row block of packed A/W (shorts)

// ---------------- pack activations (80 rows x 12800) f32 -> bf16 tiles (initial only)
__global__ __launch_bounds__(256) void k_packa(
    const float* __restrict__ src, short* __restrict__ dst) {
  int bid = blockIdx.x;            // rb*8 + kc, RB=5
  int rb = bid / 8;
  int kc = bid % 8;
  int t = threadIdx.x;
  int r = t >> 4, c = t & 15;
  long srow = ((long)rb * 16 + r) * PD;
  for (int kk = 0; kk < 25; ++kk) {
    int k = kc * 1600 + kk * 64 + c * 4;
    float4 v = *(const float4*)(src + srow + k);
    short4v o;
    o[0] = f2bf(v.x); o[1] = f2bf(v.y); o[2] = f2bf(v.z); o[3] = f2bf(v.w);
    long di = (((long)rb * 1600 + (k >> 3)) * 16 + r) * 8 + (k & 7);
    *(short4v*)(dst + di) = o;
  }
}

// ---------------- step-0 fused GEMM: stage f32 weights via 4x gload16 (4 rows x 256B
// segments per instr, xor-swizzled source), convert in compute phase, MFMA, and emit
// packed bf16 weights for steps 1-2.
__global__ __launch_bounds__(256) void k_gemm_f(
    const float* __restrict__ td_w, const float* __restrict__ bu_w,
    const short* __restrict__ Ap, short* __restrict__ wtd, short* __restrict__ wbu,
    float* __restrict__ ytd, float* __restrict__ ybu) {
  int bid = blockIdx.x;            // which*800 + kc*200 + nb
  int which = bid / 800;
  int r = bid % 800;
  int kc = r / 200;
  int nb = r % 200;
  int w = threadIdx.x >> 6;
  int lane = threadIdx.x & 63;
  int l15 = lane & 15, l4 = lane >> 4;
  const float* W = which ? bu_w : td_w;
  long ldw = which ? PD : KTD;
  short* WP = which ? wbu : wtd;
  float* Y = which ? ybu : ytd;
  int lev0 = which ? 0 : 1;
  int nb16 = nb * 4 + w;
  __shared__ float lBf[2][4096];   // per wave: [col 16][k 64] f32, k xor-swizzled by col
  __shared__ short lA[2][4096];    // [level][kg 0..7][row 16][k 8] bf16
  // B source: instr q covers cols q*4+(lane>>4); content chunk g holds source chunk g^(c&7)
  const float* bsrc[4];
#pragma unroll
  for (int q = 0; q < 4; ++q) {
    int c = q * 4 + (lane >> 4);
    bsrc[q] = W + (long)(nb16 * 16 + c) * ldw + kc * 3200
            + (((lane & 15) * 4) ^ ((c & 7) * 8));
  }
  const short* sA = Ap + (long)(lev0 + w) * MSTRIDE + (long)kc * 51200 + lane * 8;
  short* wp = WP + (long)nb16 * MSTRIDE + (((long)kc * 400 + l4) * 16 + l15) * 8;
  int lbase = w * 1024;            // wave-uniform offset (floats / shorts)
#define STAGE_F(bufi) { \
  float* bdst = lBf[bufi]; short* adst = lA[bufi]; \
  gload16(bsrc[0], bdst + lbase); \
  gload16(bsrc[1], bdst + lbase + 256); \
  gload16(bsrc[2], bdst + lbase + 512); \
  gload16(bsrc[3], bdst + lbase + 768); \
  gload16(sA, adst + lbase); \
  gload16(sA + 512, adst + lbase + 512); \
  bsrc[0] += 64; bsrc[1] += 64; bsrc[2] += 64; bsrc[3] += 64; \
  sA += 1024; }
  STAGE_F(0)
  f32x4 acc0 = {0,0,0,0}, acc1 = {0,0,0,0}, acc2 = {0,0,0,0}, acc3 = {0,0,0,0};
  int bswz = (l15 & 7) * 8;
  for (int s = 0; s < 50; ++s) {
    __syncthreads();               // stage(s) landed for all waves
    int cur = s & 1;
    if (s < 49) STAGE_F(cur ^ 1)
#pragma unroll
    for (int ks = 0; ks < 2; ++ks) {
      int fb_ = lbase + l15 * 64 + ((ks * 32 + l4 * 8) ^ bswz);
      float4 b0 = *(const float4*)&lBf[cur][fb_];
      float4 b1 = *(const float4*)&lBf[cur][fb_ + 4];
      short8 bF = cvt8(b0, b1);
      *(short8*)(wp + (long)(s * 8 + ks * 4) * 128) = bF;   // emit packed weights
      int off = ks * 512 + l4 * 128 + l15 * 8;
      short8 a0 = *(const short8*)&lA[cur][0 * 1024 + off];
      short8 a1 = *(const short8*)&lA[cur][1 * 1024 + off];
      short8 a2 = *(const short8*)&lA[cur][2 * 1024 + off];
      short8 a3 = *(const short8*)&lA[cur][3 * 1024 + off];
      acc0 = __builtin_amdgcn_mfma_f32_16x16x32_bf16(a0, bF, acc0, 0, 0, 0);
      acc1 = __builtin_amdgcn_mfma_f32_16x16x32_bf16(a1, bF, acc1, 0, 0, 0);
      acc2 = __builtin_amdgcn_mfma_f32_16x16x32_bf16(a2, bF, acc2, 0, 0, 0);
      acc3 = __builtin_amdgcn_mfma_f32_16x16x32_bf16(a3, bF, acc3, 0, 0, 0);
    }
  }
#undef STAGE_F
  float* yb = Y + (long)kc * 64 * PD;
  int col = nb16 * 16 + l15;
#pragma unroll
  for (int j = 0; j < 4; ++j) yb[(long)(0 * 16 + l4 * 4 + j) * PD + col] = acc0[j];
#pragma unroll
  for (int j = 0; j < 4; ++j) yb[(long)(1 * 16 + l4 * 4 + j) * PD + col] = acc1[j];
#pragma unroll
  for (int j = 0; j < 4; ++j) yb[(long)(2 * 16 + l4 * 4 + j) * PD + col] = acc2[j];
#pragma unroll
  for (int j = 0; j < 4; ++j) yb[(long)(3 * 16 + l4 * 4 + j) * PD + col] = acc3[j];
}

// ---------------- packed bf16 GEMM: global_load_lds double-buffered staging
__global__ __launch_bounds__(256) void k_gemm_p(
    const short* __restrict__ Ap, const short* __restrict__ wtd,
    const short* __restrict__ wbu, float* __restrict__ ytd, float* __restrict__ ybu) {
  int bid = blockIdx.x;            // which*800 + kc*200 + nb
  int which = bid / 800;
  int r = bid % 800;
  int kc = r / 200;
  int nb = r % 200;
  int w = threadIdx.x >> 6;
  int lane = threadIdx.x & 63;
  int l15 = lane & 15, l4 = lane >> 4;
  const short* Wp = which ? wbu : wtd;
  float* Y = which ? ybu : ytd;
  int lev0 = which ? 0 : 1;
  int nb16 = nb * 4 + w;
  __shared__ short lA[2][4096];
  __shared__ short lB[2][4096];
  const short* sB = Wp + (long)nb16 * MSTRIDE + (long)kc * 51200 + lane * 8;
  const short* sA = Ap + (long)(lev0 + w) * MSTRIDE + (long)kc * 51200 + lane * 8;
  int lbase = w * 1024;
#define STAGE_G(bufi) { \
  gload16(sB,       &lB[bufi][lbase]); \
  gload16(sB + 512, &lB[bufi][lbase + 512]); \
  gload16(sA,       &lA[bufi][lbase]); \
  gload16(sA + 512, &lA[bufi][lbase + 512]); \
  sB += 1024; sA += 1024; }
  STAGE_G(0)
  f32x4 acc0 = {0,0,0,0}, acc1 = {0,0,0,0}, acc2 = {0,0,0,0}, acc3 = {0,0,0,0};
  int fo = l4 * 128 + l15 * 8;
  for (int s = 0; s < 50; ++s) {
    __syncthreads();
    int cur = s & 1;
    if (s < 49) STAGE_G(cur ^ 1)
#pragma unroll
    for (int ks = 0; ks < 2; ++ks) {
      int off = ks * 512 + fo;
      short8 bF = *(const short8*)&lB[cur][w * 1024 + off];
      short8 a0 = *(const short8*)&lA[cur][0 * 1024 + off];
      short8 a1 = *(const short8*)&lA[cur][1 * 1024 + off];
      short8 a2 = *(const short8*)&lA[cur][2 * 1024 + off];
      short8 a3 = *(const short8*)&lA[cur][3 * 1024 + off];
      acc0 = __builtin_amdgcn_mfma_f32_16x16x32_bf16(a0, bF, acc0, 0, 0, 0);
      acc1 = __builtin_amdgcn_mfma_f32_16x16x32_bf16(a1, bF, acc1, 0, 0, 0);
      acc2 = __builtin_amdgcn_mfma_f32_16x16x32_bf16(a2, bF, acc2, 0, 0, 0);
      acc3 = __builtin_amdgcn_mfma_f32_16x16x32_bf16(a3, bF, acc3, 0, 0, 0);
    }
  }
#undef STAGE_G
  float* yb = Y + (long)kc * 64 * PD;
  int col = nb16 * 16 + l15;
#pragma unroll
  for (int j = 0; j < 4; ++j) yb[(long)(0 * 16 + l4 * 4 + j) * PD + col] = acc0[j];
#pragma unroll
  for (int j = 0; j < 4; ++j) yb[(long)(1 * 16 + l4 * 4 + j) * PD + col] = acc1[j];
#pragma unroll
  for (int j = 0; j < 4; ++j) yb[(long)(2 * 16 + l4 * 4 + j) * PD + col] = acc2[j];
#pragma unroll
  for (int j = 0; j < 4; ++j) yb[(long)(3 * 16 + l4 * 4 + j) * PD + col] = acc3[j];
}

// ---------------- fallback f32-stream GEMM (used only if ws too small to pack)
__global__ __launch_bounds__(256) void k_gemm(
    const float* __restrict__ cols, const float* __restrict__ td_w,
    const float* __restrict__ bu_w, float* __restrict__ ytd, float* __restrict__ ybu) {
  int bid = blockIdx.x;            // 0..1599
  int which = bid / 800;
  int r = bid % 800;
  int kc = r / 200;
  int nb = r % 200;
  const float* X; const float* W; long ldw; float* Y;
  if (which == 0) { X = cols + BPD; W = td_w; ldw = KTD; Y = ytd; }
  else            { X = cols;       W = bu_w; ldw = PD;  Y = ybu; }
  int wave = threadIdx.x >> 6;
  int lane = threadIdx.x & 63;
  int l15 = lane & 15, l4 = lane >> 4;
  int n0 = nb * 64 + wave * 16;
  int k0 = kc * 3200 + l4 * 8;
  const float* ap = X + (long)l15 * PD + k0;
  const float* bp = W + (long)(n0 + l15) * ldw + k0;
  f32x4 acc[4] = {{0,0,0,0},{0,0,0,0},{0,0,0,0},{0,0,0,0}};
  for (int kk = 0; kk < 100; ++kk) {
    float4 b0 = *(const float4*)bp;
    float4 b1 = *(const float4*)(bp + 4);
    short8 bf = cvt8(b0, b1);
#pragma unroll
    for (int m = 0; m < 4; ++m) {
      const float* a_ = ap + (long)m * 16 * PD;
      float4 a0 = *(const float4*)a_;
      float4 a1 = *(const float4*)(a_ + 4);
      short8 af = cvt8(a0, a1);
      acc[m] = __builtin_amdgcn_mfma_f32_16x16x32_bf16(af, bf, acc[m], 0, 0, 0);
    }
    ap += 32; bp += 32;
  }
  float* yb = Y + (long)kc * 64 * PD;
  int col = n0 + l15;
#pragma unroll
  for (int m = 0; m < 4; ++m)
#pragma unroll
    for (int j = 0; j < 4; ++j)
      yb[(long)(m * 16 + l4 * 4 + j) * PD + col] = acc[m][j];
}

// ---------------- mega-fused attention + combine + next-step A packing
// grid 80 = (i*16+b); 512 threads (2 waves/SIMD); 153.6 KB LDS.
__global__ __launch_bounds__(512) void k_att(
    const float* __restrict__ cols,
    const float* __restrict__ qw, const float* __restrict__ qb,
    const float* __restrict__ kw, const float* __restrict__ kb,
    const float* __restrict__ vw, const float* __restrict__ vb,
    const float* __restrict__ ytd, const float* __restrict__ ybu,
    const float* __restrict__ tdbias, const float* __restrict__ bub,
    const float* __restrict__ gamma,
    float* __restrict__ colsn, short* __restrict__ apack, int emit) {
  __shared__ float smem[38400];    // 153.6 KB
  float* T1 = smem;                // [100][128]
  float* V  = smem + 12800;        // [100][128]
  float* OL = smem + 25600;        // [100][128] (written in PV phase)
  float* QG = smem + 25600;        // [10][128]  (dead before OL writes)
  float* KG = smem + 26880;        // [10][128]
  float* WB = smem + 28160;        // [300]
  int ib = blockIdx.x;
  int i = ib >> 4, b = ib & 15;
  int t = threadIdx.x;
  const float* t1b = cols + (long)ib * PD;
  for (int idx = t; idx < PD; idx += 512) T1[idx] = t1b[idx];
  if (t < 300) {
    int w3 = t / 100, c = t % 100;
    WB[t] = (w3 == 0 ? qw[c] : w3 == 1 ? kw[c] : vw[c]);
  }
  __syncthreads();
  int s = t & 127, oq = t >> 7;    // gconv mapping: up to 3 o-reps per thread
  int mq = t & 3, n = t >> 2;      // logits/PV mapping: one n-row per thread
  float acc0[32];
#pragma unroll
  for (int j = 0; j < 32; ++j) acc0[j] = 0.f;
  for (int g = 0; g < 10; ++g) {
    float aq[3], ak[3], av[3];
#pragma unroll
    for (int r = 0; r < 3; ++r) {
      int o = r * 4 + oq;
      if (o < 10) { int p = g * 10 + o; aq[r] = qb[p]; ak[r] = kb[p]; av[r] = vb[p]; }
      else { aq[r] = 0.f; ak[r] = 0.f; av[r] = 0.f; }
    }
    for (int c = 0; c < 10; ++c) {
      float z = T1[(g * 10 + c) * 128 + s];
#pragma unroll
      for (int r = 0; r < 3; ++r) {
        int o = r * 4 + oq;
        if (o < 10) {
          aq[r] += WB[o * 10 + c] * z;
          ak[r] += WB[100 + o * 10 + c] * z;
          av[r] += WB[200 + o * 10 + c] * z;
        }
      }
    }
    __syncthreads();   // WB reads done; prior logits reads of QG/KG done (loop-end bar)
#pragma unroll
    for (int r = 0; r < 3; ++r) {
      int o = r * 4 + oq;
      if (o < 10) {
        QG[o * 128 + s] = aq[r];
        KG[o * 128 + s] = ak[r];
        V[(g * 10 + o) * 128 + s] = av[r];
      }
    }
    if (g < 9 && t < 300) {
      int w3 = t / 100, c = t % 100;
      int gi = (g + 1) * 100 + c;
      WB[t] = (w3 == 0 ? qw[gi] : w3 == 1 ? kw[gi] : vw[gi]);
    }
    __syncthreads();   // QG/KG + WB ready
    const float4* K4 = (const float4*)KG;
    for (int c = 0; c < 10; ++c) {
      float qa = QG[c * 128 + n];
#pragma unroll
      for (int jj = 0; jj < 8; ++jj) {
        float4 kv = K4[c * 32 + mq * 8 + jj];
        acc0[jj * 4 + 0] += qa * kv.x; acc0[jj * 4 + 1] += qa * kv.y;
        acc0[jj * 4 + 2] += qa * kv.z; acc0[jj * 4 + 3] += qa * kv.w;
      }
    }
    __syncthreads();   // QG/KG reads done before next g overwrites
  }
  // softmax over m (row n): 4 lanes per row (mq = lane bits 0-1)
  {
    float mx = acc0[0];
#pragma unroll
    for (int j = 1; j < 32; ++j) mx = fmaxf(mx, acc0[j]);
    mx = fmaxf(mx, __shfl_xor(mx, 1)); mx = fmaxf(mx, __shfl_xor(mx, 2));
    float sm = 0.f;
#pragma unroll
    for (int j = 0; j < 32; ++j) { acc0[j] = __expf(acc0[j] - mx); sm += acc0[j]; }
    sm += __shfl_xor(sm, 1); sm += __shfl_xor(sm, 2);
    float inv = 1.0f / sm;
#pragma unroll
    for (int j = 0; j < 32; ++j) acc0[j] *= inv;
  }
  // PV: O[p][n] = sum_m V[p][m] * A[n][m]; butterfly over mq; owner writes to LDS
  const float4* V4 = (const float4*)V;
  for (int p = 0; p < 100; ++p) {
    float pa = 0.f;
#pragma unroll
    for (int jj = 0; jj < 8; ++jj) {
      float4 vv = V4[p * 32 + mq * 8 + jj];
      pa += acc0[jj * 4 + 0] * vv.x + acc0[jj * 4 + 1] * vv.y
          + acc0[jj * 4 + 2] * vv.z + acc0[jj * 4 + 3] * vv.w;
    }
    pa += __shfl_xor(pa, 1); pa += __shfl_xor(pa, 2);
    if ((p & 3) == mq) OL[p * 128 + n] = pa;
  }
  __syncthreads();
  // combine + emit packed bf16 A for next step
  float gam = gamma[0];
  bool has_td = (i < EE - 1);
  bool has_bu = (i > 0);
  const float* ytdr = ytd + ((long)i * BB + b) * PD;
  const float* ybur = ybu + ((long)(i - 1) * BB + b) * PD;
  const long CH = 64L * PD;
  float* outb = colsn + (long)ib * PD;
  short* ap_ = apack;
  for (int od = t; od < PD; od += 512) {
    float t1 = T1[od];
    float ov = OL[od];
    float accv = t1 + 0.33f * (gam * ov + t1);
    if (has_td) {
      float y = tdbias[od] + ytdr[od] + ytdr[CH + od] + ytdr[2 * CH + od] + ytdr[3 * CH + od];
      accv += 0.33f * y;
    }
    if (has_bu) {
      float y = bub[od] + ybur[od] + ybur[CH + od] + ybur[2 * CH + od] + ybur[3 * CH + od];
      accv += 0.33f * y;
    }
    outb[od] = accv;
    if (emit)
      ap_[(((long)i * 1600 + (od >> 3)) * 16 + b) * 8 + (od & 7)] = f2bf(accv);
  }
}

// ---------------- final: out[b][d] = mean_p cols[level 4][b][p][d]
__global__ __launch_bounds__(128) void k_mean(const float* __restrict__ cols, float* __restrict__ out) {
  int b = blockIdx.x, d = threadIdx.x;
  const float* base = cols + ((long)4 * BB + b) * PP * DD + d;
  float s0 = 0.f, s1 = 0.f, s2 = 0.f, s3 = 0.f;
  for (int p = 0; p < 100; p += 4) {
    s0 += base[(long)p * DD];
    s1 += base[(long)(p + 1) * DD];
    s2 += base[(long)(p + 2) * DD];
    s3 += base[(long)(p + 3) * DD];
  }
  out[b * DD + d] = (s0 + s1 + s2 + s3) / 100.0f;
}

extern "C" void kernel_launch(void* const* d_in, const int* in_sizes, int n_in,
                              void* d_out, int out_size, void* d_ws, size_t ws_size,
                              hipStream_t stream) {
  const float* x     = (const float*)d_in[0];
  const float* cnn_w = (const float*)d_in[1];
  const float* cnn_b = (const float*)d_in[2];
  const float* fc_w  = (const float*)d_in[3];
  const float* fc_b  = (const float*)d_in[4];
  const float* td_w  = (const float*)d_in[5];
  const float* td_b  = (const float*)d_in[6];
  const float* bu_w  = (const float*)d_in[7];
  const float* bu_b  = (const float*)d_in[8];
  const float* qw    = (const float*)d_in[9];
  const float* qb    = (const float*)d_in[10];
  const float* kw    = (const float*)d_in[11];
  const float* kb    = (const float*)d_in[12];
  const float* vw    = (const float*)d_in[13];
  const float* vb    = (const float*)d_in[14];
  const float* gamma = (const float*)d_in[15];
  float* out = (float*)d_out;
  float* ws = (float*)d_ws;

  float* cols_a = ws;                     // 1,024,000
  float* cols_b = ws + 1024000;           // 1,024,000
  float* ytd    = ws + 6430720;           // 3,276,800
  float* ybu    = ws + 9707520;           // 3,276,800
  float* tdbias = ws + 12984320;          // 12,800
  // packed bf16 region (shorts)
  short* wtd_p  = (short*)(ws + 12997120);          // 163,840,000 shorts
  short* wbu_p  = wtd_p + 163840000;                // 163,840,000 shorts
  short* apack  = wbu_p + 163840000;                // 1,024,000 shorts (+8192 pad)
  size_t need_bytes = (size_t)12997120 * 4 + (163840000ULL * 2 + 1024000ULL + 8192ULL) * 2;
  bool packed = ws_size >= need_bytes;

  k_encoder<<<1600, 128, 0, stream>>>(x, cnn_w, cnn_b, fc_w, fc_b, cols_a);
  k_tdbias<<<50, 256, 0, stream>>>(td_w, td_b, tdbias);
  if (packed) k_packa<<<40, 256, 0, stream>>>(cols_a, apack);

  float* cur = cols_a;
  float* nxt = cols_b;
  for (int t = 0; t < 3; ++t) {
    if (packed) {
      if (t == 0)
        k_gemm_f<<<1600, 256, 0, stream>>>(td_w, bu_w, apack, wtd_p, wbu_p, ytd, ybu);
      else
        k_gemm_p<<<1600, 256, 0, stream>>>(apack, wtd_p, wbu_p, ytd, ybu);
    } else {
      k_gemm<<<1600, 256, 0, stream>>>(cur, td_w, bu_w, ytd, ybu);
    }
    int emit = (packed && t < 2) ? 1 : 0;
    k_att<<<80, 512, 0, stream>>>(cur, qw, qb, kw, kb, vw, vb,
                                  ytd, ybu, tdbias, bu_b, gamma, nxt, apack, emit);
    float* tmp = cur; cur = nxt; nxt = tmp;
  }
  k_mean<<<16, 128, 0, stream>>>(cur, out);
}

// Round 14
// 1039.154 us; speedup vs baseline: 1.4039x; 1.0314x over previous
//
#include <hip/hip_runtime.h>

#define BB 16
#define PP 100
#define EE 5
#define DD 128
#define GG 10
#define PD 12800      // P*D
#define KTD 12900     // PD + P
#define BPD (BB*PD)   // floats per level slab

typedef __attribute__((ext_vector_type(4))) float f32x4;
typedef __attribute__((ext_vector_type(8))) short short8;
typedef __attribute__((ext_vector_type(4))) short short4v;

static __device__ __forceinline__ short f2bf(float f) {
  unsigned u = __builtin_bit_cast(unsigned, f);
  u += 0x7FFFu + ((u >> 16) & 1u);
  return (short)(u >> 16);
}

static __device__ __forceinline__ short8 cvt8(float4 a, float4 b) {
  short8 r;
  r[0] = f2bf(a.x); r[1] = f2bf(a.y); r[2] = f2bf(a.z); r[3] = f2bf(a.w);
  r[4] = f2bf(b.x); r[5] = f2bf(b.y); r[6] = f2bf(b.z); r[7] = f2bf(b.w);
  return r;
}

// fire-and-forget global->LDS DMA. lds base must be wave-uniform; HW adds lane*size.
static __device__ __forceinline__ void gload16(const void* g, void* l) {
  __builtin_amdgcn_global_load_lds((const __attribute__((address_space(1))) void*)g,
                                   (__attribute__((address_space(3))) void*)l, 16, 0, 0);
}

// ---------------- encoder: patches -> conv -> relu -> fc -> broadcast to 5 levels
__global__ __launch_bounds__(128) void k_encoder(
    const float* __restrict__ x, const float* __restrict__ cw, const float* __restrict__ cb,
    const float* __restrict__ fw, const float* __restrict__ fb, float* __restrict__ cols) {
  int bid = blockIdx.x;            // b*100 + p
  int b = bid / 100, p = bid % 100;
  int py = p / 10, px = p % 10;
  __shared__ float patch[9];
  __shared__ float h[32];
  int tid = threadIdx.x;
  if (tid < 9) {
    int ii = tid / 3, jj = tid % 3;
    int gr = py * 3 + ii - 1, gc = px * 3 + jj - 1;
    float v = 0.f;
    if (gr >= 0 && gr < 28 && gc >= 0 && gc < 28) v = x[b * 784 + gr * 28 + gc];
    patch[tid] = v;
  }
  __syncthreads();
  if (tid < 32) {
    float a = cb[tid];
#pragma unroll
    for (int t = 0; t < 9; ++t) a += patch[t] * cw[tid * 9 + t];
    h[tid] = fmaxf(a, 0.f);
  }
  __syncthreads();
  float e = fb[tid];
#pragma unroll
  for (int o = 0; o < 32; ++o) e += h[o] * fw[tid * 32 + o];
  long bp = (long)b * PP + p;
  for (int lev = 0; lev < EE; ++lev)
    cols[((long)lev * BB * PP + bp) * DD + tid] = e;
}

// ---------------- fold pos columns of td_w into bias (pos is constant = arange(P))
__global__ __launch_bounds__(256) void k_tdbias(
    const float* __restrict__ td_w, const float* __restrict__ td_b, float* __restrict__ out) {
  int o = blockIdx.x * 256 + threadIdx.x;
  if (o >= PD) return;
  float s = td_b[o];
  const float4* r = (const float4*)(td_w + (long)o * KTD + PD);
#pragma unroll
  for (int q = 0; q < 25; ++q) {
    float4 v = r[q];
    float p0 = (float)(q * 4);
    s += p0 * v.x + (p0 + 1.f) * v.y + (p0 + 2.f) * v.z + (p0 + 3.f) * v.w;
  }
  out[o] = s;
}

#define MSTRIDE (1600L * 16 * 8)   // one 16-row block of packed A/W (shorts)

// ---------------- pack activations (80 rows x 12800) f32 -> bf16 tiles (initial only)
__global__ __launch_bounds__(256) void k_packa(
    const float* __restrict__ src, short* __restrict__ dst) {
  int bid = blockIdx.x;            // rb*8 + kc, RB=5
  int rb = bid / 8;
  int kc = bid % 8;
  int t = threadIdx.x;
  int r = t >> 4, c = t & 15;
  long srow = ((long)rb * 16 + r) * PD;
  for (int kk = 0; kk < 25; ++kk) {
    int k = kc * 1600 + kk * 64 + c * 4;
    float4 v = *(const float4*)(src + srow + k);
    short4v o;
    o[0] = f2bf(v.x); o[1] = f2bf(v.y); o[2] = f2bf(v.z); o[3] = f2bf(v.w);
    long di = (((long)rb * 1600 + (k >> 3)) * 16 + r) * 8 + (k & 7);
    *(short4v*)(dst + di) = o;
  }
}

// ---------------- step-0 fused GEMM: stage f32 weights via 4x gload16 (4 rows x 256B
// segments per instr, xor-swizzled source), convert in compute phase, MFMA, and emit
// packed bf16 weights for steps 1-2.
__global__ __launch_bounds__(256) void k_gemm_f(
    const float* __restrict__ td_w, const float* __restrict__ bu_w,
    const short* __restrict__ Ap, short* __restrict__ wtd, short* __restrict__ wbu,
    float* __restrict__ ytd, float* __restrict__ ybu) {
  int bid = blockIdx.x;            // which*800 + kc*200 + nb
  int which = bid / 800;
  int r = bid % 800;
  int kc = r / 200;
  int nb = r % 200;
  int w = threadIdx.x >> 6;
  int lane = threadIdx.x & 63;
  int l15 = lane & 15, l4 = lane >> 4;
  const float* W = which ? bu_w : td_w;
  long ldw = which ? PD : KTD;
  short* WP = which ? wbu : wtd;
  float* Y = which ? ybu : ytd;
  int lev0 = which ? 0 : 1;
  int nb16 = nb * 4 + w;
  __shared__ float lBf[2][4096];   // per wave: [col 16][k 64] f32, k xor-swizzled by col
  __shared__ short lA[2][4096];    // [level][kg 0..7][row 16][k 8] bf16
  // B source: instr q covers cols q*4+(lane>>4); content chunk g holds source chunk g^(c&7)
  const float* bsrc[4];
#pragma unroll
  for (int q = 0; q < 4; ++q) {
    int c = q * 4 + (lane >> 4);
    bsrc[q] = W + (long)(nb16 * 16 + c) * ldw + kc * 3200
            + (((lane & 15) * 4) ^ ((c & 7) * 8));
  }
  const short* sA = Ap + (long)(lev0 + w) * MSTRIDE + (long)kc * 51200 + lane * 8;
  short* wp = WP + (long)nb16 * MSTRIDE + (((long)kc * 400 + l4) * 16 + l15) * 8;
  int lbase = w * 1024;            // wave-uniform offset (floats / shorts)
#define STAGE_F(bufi) { \
  float* bdst = lBf[bufi]; short* adst = lA[bufi]; \
  gload16(bsrc[0], bdst + lbase); \
  gload16(bsrc[1], bdst + lbase + 256); \
  gload16(bsrc[2], bdst + lbase + 512); \
  gload16(bsrc[3], bdst + lbase + 768); \
  gload16(sA, adst + lbase); \
  gload16(sA + 512, adst + lbase + 512); \
  bsrc[0] += 64; bsrc[1] += 64; bsrc[2] += 64; bsrc[3] += 64; \
  sA += 1024; }
  STAGE_F(0)
  f32x4 acc0 = {0,0,0,0}, acc1 = {0,0,0,0}, acc2 = {0,0,0,0}, acc3 = {0,0,0,0};
  int bswz = (l15 & 7) * 8;
  for (int s = 0; s < 50; ++s) {
    __syncthreads();               // stage(s) landed for all waves
    int cur = s & 1;
    if (s < 49) STAGE_F(cur ^ 1)
#pragma unroll
    for (int ks = 0; ks < 2; ++ks) {
      int fb_ = lbase + l15 * 64 + ((ks * 32 + l4 * 8) ^ bswz);
      float4 b0 = *(const float4*)&lBf[cur][fb_];
      float4 b1 = *(const float4*)&lBf[cur][fb_ + 4];
      short8 bF = cvt8(b0, b1);
      *(short8*)(wp + (long)(s * 8 + ks * 4) * 128) = bF;   // emit packed weights
      int off = ks * 512 + l4 * 128 + l15 * 8;
      short8 a0 = *(const short8*)&lA[cur][0 * 1024 + off];
      short8 a1 = *(const short8*)&lA[cur][1 * 1024 + off];
      short8 a2 = *(const short8*)&lA[cur][2 * 1024 + off];
      short8 a3 = *(const short8*)&lA[cur][3 * 1024 + off];
      acc0 = __builtin_amdgcn_mfma_f32_16x16x32_bf16(a0, bF, acc0, 0, 0, 0);
      acc1 = __builtin_amdgcn_mfma_f32_16x16x32_bf16(a1, bF, acc1, 0, 0, 0);
      acc2 = __builtin_amdgcn_mfma_f32_16x16x32_bf16(a2, bF, acc2, 0, 0, 0);
      acc3 = __builtin_amdgcn_mfma_f32_16x16x32_bf16(a3, bF, acc3, 0, 0, 0);
    }
  }
#undef STAGE_F
  float* yb = Y + (long)kc * 64 * PD;
  int col = nb16 * 16 + l15;
#pragma unroll
  for (int j = 0; j < 4; ++j) yb[(long)(0 * 16 + l4 * 4 + j) * PD + col] = acc0[j];
#pragma unroll
  for (int j = 0; j < 4; ++j) yb[(long)(1 * 16 + l4 * 4 + j) * PD + col] = acc1[j];
#pragma unroll
  for (int j = 0; j < 4; ++j) yb[(long)(2 * 16 + l4 * 4 + j) * PD + col] = acc2[j];
#pragma unroll
  for (int j = 0; j < 4; ++j) yb[(long)(3 * 16 + l4 * 4 + j) * PD + col] = acc3[j];
}

// ---------------- packed bf16 GEMM: global_load_lds double-buffered staging
__global__ __launch_bounds__(256) void k_gemm_p(
    const short* __restrict__ Ap, const short* __restrict__ wtd,
    const short* __restrict__ wbu, float* __restrict__ ytd, float* __restrict__ ybu) {
  int bid = blockIdx.x;            // which*800 + kc*200 + nb
  int which = bid / 800;
  int r = bid % 800;
  int kc = r / 200;
  int nb = r % 200;
  int w = threadIdx.x >> 6;
  int lane = threadIdx.x & 63;
  int l15 = lane & 15, l4 = lane >> 4;
  const short* Wp = which ? wbu : wtd;
  float* Y = which ? ybu : ytd;
  int lev0 = which ? 0 : 1;
  int nb16 = nb * 4 + w;
  __shared__ short lA[2][4096];
  __shared__ short lB[2][4096];
  const short* sB = Wp + (long)nb16 * MSTRIDE + (long)kc * 51200 + lane * 8;
  const short* sA = Ap + (long)(lev0 + w) * MSTRIDE + (long)kc * 51200 + lane * 8;
  int lbase = w * 1024;
#define STAGE_G(bufi) { \
  gload16(sB,       &lB[bufi][lbase]); \
  gload16(sB + 512, &lB[bufi][lbase + 512]); \
  gload16(sA,       &lA[bufi][lbase]); \
  gload16(sA + 512, &lA[bufi][lbase + 512]); \
  sB += 1024; sA += 1024; }
  STAGE_G(0)
  f32x4 acc0 = {0,0,0,0}, acc1 = {0,0,0,0}, acc2 = {0,0,0,0}, acc3 = {0,0,0,0};
  int fo = l4 * 128 + l15 * 8;
  for (int s = 0; s < 50; ++s) {
    __syncthreads();
    int cur = s & 1;
    if (s < 49) STAGE_G(cur ^ 1)
#pragma unroll
    for (int ks = 0; ks < 2; ++ks) {
      int off = ks * 512 + fo;
      short8 bF = *(const short8*)&lB[cur][w * 1024 + off];
      short8 a0 = *(const short8*)&lA[cur][0 * 1024 + off];
      short8 a1 = *(const short8*)&lA[cur][1 * 1024 + off];
      short8 a2 = *(const short8*)&lA[cur][2 * 1024 + off];
      short8 a3 = *(const short8*)&lA[cur][3 * 1024 + off];
      acc0 = __builtin_amdgcn_mfma_f32_16x16x32_bf16(a0, bF, acc0, 0, 0, 0);
      acc1 = __builtin_amdgcn_mfma_f32_16x16x32_bf16(a1, bF, acc1, 0, 0, 0);
      acc2 = __builtin_amdgcn_mfma_f32_16x16x32_bf16(a2, bF, acc2, 0, 0, 0);
      acc3 = __builtin_amdgcn_mfma_f32_16x16x32_bf16(a3, bF, acc3, 0, 0, 0);
    }
  }
#undef STAGE_G
  float* yb = Y + (long)kc * 64 * PD;
  int col = nb16 * 16 + l15;
#pragma unroll
  for (int j = 0; j < 4; ++j) yb[(long)(0 * 16 + l4 * 4 + j) * PD + col] = acc0[j];
#pragma unroll
  for (int j = 0; j < 4; ++j) yb[(long)(1 * 16 + l4 * 4 + j) * PD + col] = acc1[j];
#pragma unroll
  for (int j = 0; j < 4; ++j) yb[(long)(2 * 16 + l4 * 4 + j) * PD + col] = acc2[j];
#pragma unroll
  for (int j = 0; j < 4; ++j) yb[(long)(3 * 16 + l4 * 4 + j) * PD + col] = acc3[j];
}

// ---------------- fallback f32-stream GEMM (used only if ws too small to pack)
__global__ __launch_bounds__(256) void k_gemm(
    const float* __restrict__ cols, const float* __restrict__ td_w,
    const float* __restrict__ bu_w, float* __restrict__ ytd, float* __restrict__ ybu) {
  int bid = blockIdx.x;            // 0..1599
  int which = bid / 800;
  int r = bid % 800;
  int kc = r / 200;
  int nb = r % 200;
  const float* X; const float* W; long ldw; float* Y;
  if (which == 0) { X = cols + BPD; W = td_w; ldw = KTD; Y = ytd; }
  else            { X = cols;       W = bu_w; ldw = PD;  Y = ybu; }
  int wave = threadIdx.x >> 6;
  int lane = threadIdx.x & 63;
  int l15 = lane & 15, l4 = lane >> 4;
  int n0 = nb * 64 + wave * 16;
  int k0 = kc * 3200 + l4 * 8;
  const float* ap = X + (long)l15 * PD + k0;
  const float* bp = W + (long)(n0 + l15) * ldw + k0;
  f32x4 acc[4] = {{0,0,0,0},{0,0,0,0},{0,0,0,0},{0,0,0,0}};
  for (int kk = 0; kk < 100; ++kk) {
    float4 b0 = *(const float4*)bp;
    float4 b1 = *(const float4*)(bp + 4);
    short8 bf = cvt8(b0, b1);
#pragma unroll
    for (int m = 0; m < 4; ++m) {
      const float* a_ = ap + (long)m * 16 * PD;
      float4 a0 = *(const float4*)a_;
      float4 a1 = *(const float4*)(a_ + 4);
      short8 af = cvt8(a0, a1);
      acc[m] = __builtin_amdgcn_mfma_f32_16x16x32_bf16(af, bf, acc[m], 0, 0, 0);
    }
    ap += 32; bp += 32;
  }
  float* yb = Y + (long)kc * 64 * PD;
  int col = n0 + l15;
#pragma unroll
  for (int m = 0; m < 4; ++m)
#pragma unroll
    for (int j = 0; j < 4; ++j)
      yb[(long)(m * 16 + l4 * 4 + j) * PD + col] = acc[m][j];
}

// ---------------- mega-fused attention + combine + next-step A packing
// grid 80 = (i*16+b); 512 threads (2 waves/SIMD); 153.6 KB LDS.
// Register-blocked 2 n-rows/thread: me=t&7 owns 16 m's; np=t>>3 owns rows np, np+64.
__global__ __launch_bounds__(512) void k_att(
    const float* __restrict__ cols,
    const float* __restrict__ qw, const float* __restrict__ qb,
    const float* __restrict__ kw, const float* __restrict__ kb,
    const float* __restrict__ vw, const float* __restrict__ vb,
    const float* __restrict__ ytd, const float* __restrict__ ybu,
    const float* __restrict__ tdbias, const float* __restrict__ bub,
    const float* __restrict__ gamma,
    float* __restrict__ colsn, short* __restrict__ apack, int emit) {
  __shared__ float smem[38400];    // 153.6 KB
  float* T1 = smem;                // [100][128]
  float* V  = smem + 12800;        // [100][128]
  float* OL = smem + 25600;        // [100][128] (written in PV phase)
  float* QG = smem + 25600;        // [10][128]  (dead before OL writes)
  float* KG = smem + 26880;        // [10][128]
  float* WB = smem + 28160;        // [300]
  int ib = blockIdx.x;
  int i = ib >> 4, b = ib & 15;
  int t = threadIdx.x;
  const float* t1b = cols + (long)ib * PD;
  for (int idx = t; idx < PD; idx += 512) T1[idx] = t1b[idx];
  if (t < 300) {
    int w3 = t / 100, c = t % 100;
    WB[t] = (w3 == 0 ? qw[c] : w3 == 1 ? kw[c] : vw[c]);
  }
  __syncthreads();
  int s = t & 127, oq = t >> 7;    // gconv mapping: up to 3 o-reps per thread
  int me = t & 7, np = t >> 3;     // logits/PV mapping: m-eighth, rows np & np+64
  float acc0[16], acc1[16];
#pragma unroll
  for (int j = 0; j < 16; ++j) { acc0[j] = 0.f; acc1[j] = 0.f; }
  for (int g = 0; g < 10; ++g) {
    float aq[3], ak[3], av[3];
#pragma unroll
    for (int r = 0; r < 3; ++r) {
      int o = r * 4 + oq;
      if (o < 10) { int p = g * 10 + o; aq[r] = qb[p]; ak[r] = kb[p]; av[r] = vb[p]; }
      else { aq[r] = 0.f; ak[r] = 0.f; av[r] = 0.f; }
    }
    for (int c = 0; c < 10; ++c) {
      float z = T1[(g * 10 + c) * 128 + s];
#pragma unroll
      for (int r = 0; r < 3; ++r) {
        int o = r * 4 + oq;
        if (o < 10) {
          aq[r] += WB[o * 10 + c] * z;
          ak[r] += WB[100 + o * 10 + c] * z;
          av[r] += WB[200 + o * 10 + c] * z;
        }
      }
    }
    __syncthreads();   // WB reads done; prior logits reads of QG/KG done (loop-end bar)
#pragma unroll
    for (int r = 0; r < 3; ++r) {
      int o = r * 4 + oq;
      if (o < 10) {
        QG[o * 128 + s] = aq[r];
        KG[o * 128 + s] = ak[r];
        V[(g * 10 + o) * 128 + s] = av[r];
      }
    }
    if (g < 9 && t < 300) {
      int w3 = t / 100, c = t % 100;
      int gi = (g + 1) * 100 + c;
      WB[t] = (w3 == 0 ? qw[gi] : w3 == 1 ? kw[gi] : vw[gi]);
    }
    __syncthreads();   // QG/KG + WB ready
    const float4* K4 = (const float4*)KG;
    for (int c = 0; c < 10; ++c) {
      float qa = QG[c * 128 + np];
      float qc = QG[c * 128 + np + 64];
#pragma unroll
      for (int jj = 0; jj < 4; ++jj) {
        float4 kv = K4[c * 32 + me * 4 + jj];
        acc0[jj * 4 + 0] += qa * kv.x; acc0[jj * 4 + 1] += qa * kv.y;
        acc0[jj * 4 + 2] += qa * kv.z; acc0[jj * 4 + 3] += qa * kv.w;
        acc1[jj * 4 + 0] += qc * kv.x; acc1[jj * 4 + 1] += qc * kv.y;
        acc1[jj * 4 + 2] += qc * kv.z; acc1[jj * 4 + 3] += qc * kv.w;
      }
    }
    __syncthreads();   // QG/KG reads done before next g overwrites
  }
  // softmax over m for the two owned rows (8 lanes per row, me in lane bits 0-2)
  {
    float mx = acc0[0];
#pragma unroll
    for (int j = 1; j < 16; ++j) mx = fmaxf(mx, acc0[j]);
    mx = fmaxf(mx, __shfl_xor(mx, 1)); mx = fmaxf(mx, __shfl_xor(mx, 2));
    mx = fmaxf(mx, __shfl_xor(mx, 4));
    float sm = 0.f;
#pragma unroll
    for (int j = 0; j < 16; ++j) { acc0[j] = __expf(acc0[j] - mx); sm += acc0[j]; }
    sm += __shfl_xor(sm, 1); sm += __shfl_xor(sm, 2); sm += __shfl_xor(sm, 4);
    float inv = 1.0f / sm;
#pragma unroll
    for (int j = 0; j < 16; ++j) acc0[j] *= inv;
  }
  {
    float mx = acc1[0];
#pragma unroll
    for (int j = 1; j < 16; ++j) mx = fmaxf(mx, acc1[j]);
    mx = fmaxf(mx, __shfl_xor(mx, 1)); mx = fmaxf(mx, __shfl_xor(mx, 2));
    mx = fmaxf(mx, __shfl_xor(mx, 4));
    float sm = 0.f;
#pragma unroll
    for (int j = 0; j < 16; ++j) { acc1[j] = __expf(acc1[j] - mx); sm += acc1[j]; }
    sm += __shfl_xor(sm, 1); sm += __shfl_xor(sm, 2); sm += __shfl_xor(sm, 4);
    float inv = 1.0f / sm;
#pragma unroll
    for (int j = 0; j < 16; ++j) acc1[j] *= inv;
  }
  // PV: O[p][n] = sum_m V[p][m] * A[n][m]; butterfly over me; owner writes to LDS
  const float4* V4 = (const float4*)V;
  for (int p = 0; p < 100; ++p) {
    float pa = 0.f, pb = 0.f;
#pragma unroll
    for (int jj = 0; jj < 4; ++jj) {
      float4 vv = V4[p * 32 + me * 4 + jj];
      pa += acc0[jj * 4 + 0] * vv.x + acc0[jj * 4 + 1] * vv.y
          + acc0[jj * 4 + 2] * vv.z + acc0[jj * 4 + 3] * vv.w;
      pb += acc1[jj * 4 + 0] * vv.x + acc1[jj * 4 + 1] * vv.y
          + acc1[jj * 4 + 2] * vv.z + acc1[jj * 4 + 3] * vv.w;
    }
    pa += __shfl_xor(pa, 1); pa += __shfl_xor(pa, 2); pa += __shfl_xor(pa, 4);
    pb += __shfl_xor(pb, 1); pb += __shfl_xor(pb, 2); pb += __shfl_xor(pb, 4);
    if ((p & 7) == me) {
      OL[p * 128 + np] = pa;
      OL[p * 128 + np + 64] = pb;
    }
  }
  __syncthreads();
  // combine + emit packed bf16 A for next step
  float gam = gamma[0];
  bool has_td = (i < EE - 1);
  bool has_bu = (i > 0);
  const float* ytdr = ytd + ((long)i * BB + b) * PD;
  const float* ybur = ybu + ((long)(i - 1) * BB + b) * PD;
  const long CH = 64L * PD;
  float* outb = colsn + (long)ib * PD;
  short* ap_ = apack;
  for (int od = t; od < PD; od += 512) {
    float t1 = T1[od];
    float ov = OL[od];
    float accv = t1 + 0.33f * (gam * ov + t1);
    if (has_td) {
      float y = tdbias[od] + ytdr[od] + ytdr[CH + od] + ytdr[2 * CH + od] + ytdr[3 * CH + od];
      accv += 0.33f * y;
    }
    if (has_bu) {
      float y = bub[od] + ybur[od] + ybur[CH + od] + ybur[2 * CH + od] + ybur[3 * CH + od];
      accv += 0.33f * y;
    }
    outb[od] = accv;
    if (emit)
      ap_[(((long)i * 1600 + (od >> 3)) * 16 + b) * 8 + (od & 7)] = f2bf(accv);
  }
}

// ---------------- final: out[b][d] = mean_p cols[level 4][b][p][d]
__global__ __launch_bounds__(128) void k_mean(const float* __restrict__ cols, float* __restrict__ out) {
  int b = blockIdx.x, d = threadIdx.x;
  const float* base = cols + ((long)4 * BB + b) * PP * DD + d;
  float s0 = 0.f, s1 = 0.f, s2 = 0.f, s3 = 0.f;
  for (int p = 0; p < 100; p += 4) {
    s0 += base[(long)p * DD];
    s1 += base[(long)(p + 1) * DD];
    s2 += base[(long)(p + 2) * DD];
    s3 += base[(long)(p + 3) * DD];
  }
  out[b * DD + d] = (s0 + s1 + s2 + s3) / 100.0f;
}

extern "C" void kernel_launch(void* const* d_in, const int* in_sizes, int n_in,
                              void* d_out, int out_size, void* d_ws, size_t ws_size,
                              hipStream_t stream) {
  const float* x     = (const float*)d_in[0];
  const float* cnn_w = (const float*)d_in[1];
  const float* cnn_b = (const float*)d_in[2];
  const float* fc_w  = (const float*)d_in[3];
  const float* fc_b  = (const float*)d_in[4];
  const float* td_w  = (const float*)d_in[5];
  const float* td_b  = (const float*)d_in[6];
  const float* bu_w  = (const float*)d_in[7];
  const float* bu_b  = (const float*)d_in[8];
  const float* qw    = (const float*)d_in[9];
  const float* qb    = (const float*)d_in[10];
  const float* kw    = (const float*)d_in[11];
  const float* kb    = (const float*)d_in[12];
  const float* vw    = (const float*)d_in[13];
  const float* vb    = (const float*)d_in[14];
  const float* gamma = (const float*)d_in[15];
  float* out = (float*)d_out;
  float* ws = (float*)d_ws;

  float* cols_a = ws;                     // 1,024,000
  float* cols_b = ws + 1024000;           // 1,024,000
  float* ytd    = ws + 6430720;           // 3,276,800
  float* ybu    = ws + 9707520;           // 3,276,800
  float* tdbias = ws + 12984320;          // 12,800
  // packed bf16 region (shorts)
  short* wtd_p  = (short*)(ws + 12997120);          // 163,840,000 shorts
  short* wbu_p  = wtd_p + 163840000;                // 163,840,000 shorts
  short* apack  = wbu_p + 163840000;                // 1,024,000 shorts (+8192 pad)
  size_t need_bytes = (size_t)12997120 * 4 + (163840000ULL * 2 + 1024000ULL + 8192ULL) * 2;
  bool packed = ws_size >= need_bytes;

  k_encoder<<<1600, 128, 0, stream>>>(x, cnn_w, cnn_b, fc_w, fc_b, cols_a);
  k_tdbias<<<50, 256, 0, stream>>>(td_w, td_b, tdbias);
  if (packed) k_packa<<<40, 256, 0, stream>>>(cols_a, apack);

  float* cur = cols_a;
  float* nxt = cols_b;
  for (int t = 0; t < 3; ++t) {
    if (packed) {
      if (t == 0)
        k_gemm_f<<<1600, 256, 0, stream>>>(td_w, bu_w, apack, wtd_p, wbu_p, ytd, ybu);
      else
        k_gemm_p<<<1600, 256, 0, stream>>>(apack, wtd_p, wbu_p, ytd, ybu);
    } else {
      k_gemm<<<1600, 256, 0, stream>>>(cur, td_w, bu_w, ytd, ybu);
    }
    int emit = (packed && t < 2) ? 1 : 0;
    k_att<<<80, 512, 0, stream>>>(cur, qw, qb, kw, kb, vw, vb,
                                  ytd, ybu, tdbias, bu_b, gamma, nxt, apack, emit);
    float* tmp = cur; cur = nxt; nxt = tmp;
  }
  k_mean<<<16, 128, 0, stream>>>(cur, out);
}